// Round 4
// baseline (602.656 us; speedup 1.0000x reference)
//
#include <hip/hip_runtime.h>
#include <math.h>

#define BB 8
#define CIN 12
#define LL 4096
#define DD 64
#define DIx 128
#define DSx 16
#define RR 10
#define KK 15
#define NCH 32      // scan chunks
#define CLEN 128    // LL/NCH
#define OUTL 40960  // LL*RR

// ---------------------------------------------------------------
// Direct conv1d, K=15, pad 7. Each thread: 4 consecutive l, COT co's.
// COT=2 -> 2x grid vs COT=4 (occupancy was the limiter at 36%).
// ---------------------------------------------------------------
template<int CI, int CO, int COT, bool LEAKY>
__global__ __launch_bounds__(256) void k_conv(const float* __restrict__ in,
        const float* __restrict__ w, const float* __restrict__ bias,
        float* __restrict__ out) {
    const int LT = 1024;
    int tid = threadIdx.x;
    int bid = blockIdx.x;
    const int nlt = LL / LT;        // 4
    const int ncog = CO / COT;
    int lt = bid % nlt;
    int cog = (bid / nlt) % ncog;
    int b = bid / (nlt * ncog);
    int l0 = lt * LT + tid * 4;
    int co0 = cog * COT;

    float acc[COT][4];
#pragma unroll
    for (int c = 0; c < COT; ++c) {
        float bv = bias[co0 + c];
#pragma unroll
        for (int j = 0; j < 4; ++j) acc[c][j] = bv;
    }

    for (int ci = 0; ci < CI; ++ci) {
        const float* inp = in + ((size_t)b * CI + ci) * LL;
        float in20[20];
#pragma unroll
        for (int q = 0; q < 5; ++q) {
            int gi = l0 - 8 + q * 4;
            if (gi >= 0 && gi + 3 < LL) {
                float4 v = *(const float4*)(inp + gi);
                in20[q*4+0] = v.x; in20[q*4+1] = v.y;
                in20[q*4+2] = v.z; in20[q*4+3] = v.w;
            } else {
#pragma unroll
                for (int j = 0; j < 4; ++j) {
                    int g = gi + j;
                    in20[q*4+j] = (g >= 0 && g < LL) ? inp[g] : 0.f;
                }
            }
        }
#pragma unroll
        for (int c = 0; c < COT; ++c) {
            const float* wp = w + ((size_t)(co0 + c) * CI + ci) * KK;
#pragma unroll
            for (int k = 0; k < KK; ++k) {
                float wv = wp[k];
#pragma unroll
                for (int j = 0; j < 4; ++j)
                    acc[c][j] += wv * in20[j + k + 1];
            }
        }
    }
#pragma unroll
    for (int c = 0; c < COT; ++c) {
        float r[4];
#pragma unroll
        for (int j = 0; j < 4; ++j) {
            float v = acc[c][j];
            if (LEAKY) v = (v >= 0.f) ? v : 0.01f * v;
            r[j] = v;
        }
        float4 v4 = make_float4(r[0], r[1], r[2], r[3]);
        *(float4*)(out + ((size_t)b * CO + co0 + c) * LL + l0) = v4;
    }
}

// ---------------------------------------------------------------
// in_proj GEMM: C(32768,256) = A^T-view * W(256,64)^T
// A is read DIRECTLY from (B,64,L) layout (no transpose kernel):
// At[k][m] = xin_bdl[b, k, l0+m], coalesced along m.
// ---------------------------------------------------------------
__global__ __launch_bounds__(256) void k_gemm_inproj(const float* __restrict__ A,
        const float* __restrict__ W, float* __restrict__ C) {
    __shared__ float At[64 * 132];
    __shared__ float Wt[64 * 132];
    int tid = threadIdx.x;
    int bid = blockIdx.x;
    int nb = bid & 1;
    int mb = bid >> 1;
    int row0 = mb * 128;
    int n0 = nb * 128;
    int b = row0 >> 12;
    int l0 = row0 & 4095;
#pragma unroll
    for (int it = 0; it < 8; ++it) {
        int idx = it * 256 + tid;
        int k = idx >> 5, m4 = (idx & 31) * 4;
        float4 v = *(const float4*)(A + ((size_t)b * DD + k) * LL + l0 + m4);
        *(float4*)&At[k * 132 + m4] = v;
    }
#pragma unroll
    for (int it = 0; it < 8; ++it) {
        int lin = it * 1024 + tid * 4;
        int n = lin >> 6, k = lin & 63;
        float4 v = *(const float4*)(W + (size_t)(n0 + n) * 64 + k);
        Wt[(k+0)*132 + n] = v.x; Wt[(k+1)*132 + n] = v.y;
        Wt[(k+2)*132 + n] = v.z; Wt[(k+3)*132 + n] = v.w;
    }
    __syncthreads();
    int tx = tid & 15, ty = tid >> 4;
    float acc[2][2][4][4] = {};
#pragma unroll 4
    for (int k = 0; k < 64; ++k) {
        float4 aLo = *(float4*)&At[k*132 + ty*4];
        float4 aHi = *(float4*)&At[k*132 + 64 + ty*4];
        float4 bLo = *(float4*)&Wt[k*132 + tx*4];
        float4 bHi = *(float4*)&Wt[k*132 + 64 + tx*4];
        float a0[4] = {aLo.x, aLo.y, aLo.z, aLo.w};
        float a1[4] = {aHi.x, aHi.y, aHi.z, aHi.w};
        float b0[4] = {bLo.x, bLo.y, bLo.z, bLo.w};
        float b1[4] = {bHi.x, bHi.y, bHi.z, bHi.w};
#pragma unroll
        for (int mm = 0; mm < 4; ++mm)
#pragma unroll
            for (int nn = 0; nn < 4; ++nn) {
                acc[0][0][mm][nn] += a0[mm] * b0[nn];
                acc[0][1][mm][nn] += a0[mm] * b1[nn];
                acc[1][0][mm][nn] += a1[mm] * b0[nn];
                acc[1][1][mm][nn] += a1[mm] * b1[nn];
            }
    }
#pragma unroll
    for (int qm = 0; qm < 2; ++qm)
#pragma unroll
        for (int mm = 0; mm < 4; ++mm) {
            int row = row0 + qm*64 + ty*4 + mm;
#pragma unroll
            for (int qn = 0; qn < 2; ++qn) {
                float4 v = make_float4(acc[qm][qn][mm][0], acc[qm][qn][mm][1],
                                       acc[qm][qn][mm][2], acc[qm][qn][mm][3]);
                *(float4*)(C + (size_t)row * 256 + n0 + qn*64 + tx*4) = v;
            }
        }
}

// ---------------------------------------------------------------
// x_proj GEMM: dbl(32768,64) = A(32768,128) * W(36,128)^T (zero-padded)
// ---------------------------------------------------------------
template<int NW, bool GUARD>
__global__ __launch_bounds__(256) void k_gemm64(const float* __restrict__ A,
        const float* __restrict__ W, float* __restrict__ out) {
    __shared__ float At[64 * 132];
    __shared__ float Wt[64 * 68];
    int tid = threadIdx.x;
    int row0 = blockIdx.x * 128;
    int tx = tid & 15, ty = tid >> 4;
    float acc[2][4][4] = {};
#pragma unroll
    for (int kt = 0; kt < 2; ++kt) {
        __syncthreads();
#pragma unroll
        for (int it = 0; it < 8; ++it) {
            int lin = it * 1024 + tid * 4;
            int m = lin >> 6, k = lin & 63;
            float4 v = *(const float4*)(A + (size_t)(row0 + m) * 128 + kt*64 + k);
            At[(k+0)*132 + m] = v.x; At[(k+1)*132 + m] = v.y;
            At[(k+2)*132 + m] = v.z; At[(k+3)*132 + m] = v.w;
        }
#pragma unroll
        for (int it = 0; it < 4; ++it) {
            int lin = it * 1024 + tid * 4;
            int n = lin >> 6, k = lin & 63;
            float4 v = make_float4(0.f, 0.f, 0.f, 0.f);
            if (!GUARD || n < NW)
                v = *(const float4*)(W + (size_t)n * 128 + kt*64 + k);
            Wt[(k+0)*68 + n] = v.x; Wt[(k+1)*68 + n] = v.y;
            Wt[(k+2)*68 + n] = v.z; Wt[(k+3)*68 + n] = v.w;
        }
        __syncthreads();
#pragma unroll 4
        for (int k = 0; k < 64; ++k) {
            float4 aLo = *(float4*)&At[k*132 + ty*4];
            float4 aHi = *(float4*)&At[k*132 + 64 + ty*4];
            float4 b4  = *(float4*)&Wt[k*68 + tx*4];
            float a0[4] = {aLo.x, aLo.y, aLo.z, aLo.w};
            float a1[4] = {aHi.x, aHi.y, aHi.z, aHi.w};
            float bv[4] = {b4.x, b4.y, b4.z, b4.w};
#pragma unroll
            for (int mm = 0; mm < 4; ++mm)
#pragma unroll
                for (int nn = 0; nn < 4; ++nn) {
                    acc[0][mm][nn] += a0[mm] * bv[nn];
                    acc[1][mm][nn] += a1[mm] * bv[nn];
                }
        }
    }
#pragma unroll
    for (int qm = 0; qm < 2; ++qm)
#pragma unroll
        for (int mm = 0; mm < 4; ++mm) {
            int row = row0 + qm*64 + ty*4 + mm;
            float4 v = make_float4(acc[qm][mm][0], acc[qm][mm][1],
                                   acc[qm][mm][2], acc[qm][mm][3]);
            *(float4*)(out + (size_t)row * 64 + tx*4) = v;
        }
}

// ---------------------------------------------------------------
// out_proj GEMM + residual + transposed write:
// out_bdl[b,d,l] = (ym(32768,128) * W(64,128)^T)[l,d] + res_bdl[b,d,l]
// Epilogue: LDS transpose (128 l x 64 d), coalesced write along l.
// ---------------------------------------------------------------
__global__ __launch_bounds__(256) void k_gemm64_tr(const float* __restrict__ A,
        const float* __restrict__ W, const float* __restrict__ res,
        float* __restrict__ out) {
    __shared__ float smem[64*132 + 64*68];   // 12800 floats
    float* At = smem;
    float* Wt = smem + 64*132;
    int tid = threadIdx.x;
    int row0 = blockIdx.x * 128;
    int tx = tid & 15, ty = tid >> 4;
    float acc[2][4][4] = {};
#pragma unroll
    for (int kt = 0; kt < 2; ++kt) {
        __syncthreads();
#pragma unroll
        for (int it = 0; it < 8; ++it) {
            int lin = it * 1024 + tid * 4;
            int m = lin >> 6, k = lin & 63;
            float4 v = *(const float4*)(A + (size_t)(row0 + m) * 128 + kt*64 + k);
            At[(k+0)*132 + m] = v.x; At[(k+1)*132 + m] = v.y;
            At[(k+2)*132 + m] = v.z; At[(k+3)*132 + m] = v.w;
        }
#pragma unroll
        for (int it = 0; it < 4; ++it) {
            int lin = it * 1024 + tid * 4;
            int n = lin >> 6, k = lin & 63;
            float4 v = *(const float4*)(W + (size_t)n * 128 + kt*64 + k);
            Wt[(k+0)*68 + n] = v.x; Wt[(k+1)*68 + n] = v.y;
            Wt[(k+2)*68 + n] = v.z; Wt[(k+3)*68 + n] = v.w;
        }
        __syncthreads();
#pragma unroll 4
        for (int k = 0; k < 64; ++k) {
            float4 aLo = *(float4*)&At[k*132 + ty*4];
            float4 aHi = *(float4*)&At[k*132 + 64 + ty*4];
            float4 b4  = *(float4*)&Wt[k*68 + tx*4];
            float a0[4] = {aLo.x, aLo.y, aLo.z, aLo.w};
            float a1[4] = {aHi.x, aHi.y, aHi.z, aHi.w};
            float bv[4] = {b4.x, b4.y, b4.z, b4.w};
#pragma unroll
            for (int mm = 0; mm < 4; ++mm)
#pragma unroll
                for (int nn = 0; nn < 4; ++nn) {
                    acc[0][mm][nn] += a0[mm] * bv[nn];
                    acc[1][mm][nn] += a1[mm] * bv[nn];
                }
        }
    }
    // transpose epilogue
    __syncthreads();
    float* tile = smem;   // 128*68 = 8704 <= 12800
#pragma unroll
    for (int qm = 0; qm < 2; ++qm)
#pragma unroll
        for (int mm = 0; mm < 4; ++mm) {
            int lrow = qm*64 + ty*4 + mm;
            *(float4*)&tile[lrow*68 + tx*4] = make_float4(
                acc[qm][mm][0], acc[qm][mm][1], acc[qm][mm][2], acc[qm][mm][3]);
        }
    __syncthreads();
    int b = row0 >> 12, l0 = row0 & 4095;
#pragma unroll
    for (int it = 0; it < 8; ++it) {
        int idx = it * 256 + tid;
        int d = idx >> 5, l4 = (idx & 31) * 4;
        size_t base = ((size_t)b * DD + d) * LL + l0 + l4;
        float4 r = *(const float4*)(res + base);
        float4 o;
        o.x = tile[(l4+0)*68 + d] + r.x;
        o.y = tile[(l4+1)*68 + d] + r.y;
        o.z = tile[(l4+2)*68 + d] + r.z;
        o.w = tile[(l4+3)*68 + d] + r.w;
        *(float4*)(out + base) = o;
    }
}

// ---------------------------------------------------------------
// Depthwise causal conv (DC=4) + silu. xz (B,L,256) cols 0..127 are xs.
// ---------------------------------------------------------------
__global__ __launch_bounds__(256) void k_dwconv(const float* __restrict__ xz,
        const float* __restrict__ w, const float* __restrict__ bias,
        float* __restrict__ xs_act) {
    int idx = blockIdx.x * 256 + threadIdx.x;   // B*L*128
    int d = idx & 127;
    int row = idx >> 7;                          // b*L + l
    int l = row & (LL - 1);
    float s = bias[d];
    const float* wp = w + d * 4;
#pragma unroll
    for (int j = 0; j < 4; ++j) {
        int li = l - 3 + j;
        if (li >= 0) s += xz[(size_t)(row - 3 + j) * 256 + d] * wp[j];
    }
    float sg = 1.f / (1.f + __expf(-s));
    xs_act[idx] = s * sg;
}

// ---------------------------------------------------------------
// Scan phase 1 (dt fused): per (b,d,s,chunk) P=prod(dA), Q=h(end|h0=0)
// 256-thread blocks = 4 waves; wave = 4 d x 16 s.
// ---------------------------------------------------------------
__global__ __launch_bounds__(256) void k_scan1(const float* __restrict__ xs,
        const float* __restrict__ dbl, const float* __restrict__ dtw,
        const float* __restrict__ dtbias, const float* __restrict__ A_log,
        float* __restrict__ P, float* __restrict__ Q) {
    int tid = threadIdx.x, lane = tid & 63;
    int s = lane & 15, dloc = lane >> 4;
    int wg = blockIdx.x * 4 + (tid >> 6);
    int c = wg & 31, dg = (wg >> 5) & 31, b = wg >> 10;
    int d = dg * 4 + dloc;
    float Ads = -__expf(A_log[d * DSx + s]);
    float4 w4 = *(const float4*)(dtw + d * 4);
    float dbias = dtbias[d];
    float h = 0.f, p = 1.f;
    int t0 = c * CLEN;
    for (int t = t0; t < t0 + CLEN; ++t) {
        size_t row = (size_t)b * LL + t;
        float4 di = *(const float4*)(dbl + row * 64);
        float dtv = di.x*w4.x + di.y*w4.y + di.z*w4.z + di.w*w4.w + dbias;
        dtv = (dtv > 15.f) ? dtv : __logf(1.f + __expf(dtv));
        float xv = xs[row * 128 + d];
        float Bv = dbl[row * 64 + 4 + s];
        float da = __expf(dtv * Ads);
        h = da * h + dtv * Bv * xv;
        p *= da;
    }
    int chain = (b * DIx + d) * DSx + s;
    P[(size_t)c * 16384 + chain] = p;
    Q[(size_t)c * 16384 + chain] = h;
}

// ---------------------------------------------------------------
// Scan phase 2: sequential prefix over chunks + zero BN stats accum.
// ---------------------------------------------------------------
__global__ __launch_bounds__(256) void k_scan2(const float* __restrict__ P,
        const float* __restrict__ Q, float* __restrict__ Hin,
        float* __restrict__ stats) {
    int chain = blockIdx.x * 256 + threadIdx.x;  // 16384
    if (blockIdx.x == 0 && threadIdx.x < 128) stats[threadIdx.x] = 0.f;
    float carry = 0.f;
    for (int c = 0; c < NCH; ++c) {
        Hin[(size_t)c * 16384 + chain] = carry;
        carry = P[(size_t)c * 16384 + chain] * carry + Q[(size_t)c * 16384 + chain];
    }
}

// ---------------------------------------------------------------
// Scan phase 3 (dt fused): recompute with h_in, emit y (+xs*D, *silu(z))
// ---------------------------------------------------------------
__global__ __launch_bounds__(256) void k_scan3(const float* __restrict__ xs,
        const float* __restrict__ dbl, const float* __restrict__ dtw,
        const float* __restrict__ dtbias, const float* __restrict__ A_log,
        const float* __restrict__ Hin, const float* __restrict__ xz,
        const float* __restrict__ Dssm, float* __restrict__ ym) {
    int tid = threadIdx.x, lane = tid & 63;
    int s = lane & 15, dloc = lane >> 4;
    int wg = blockIdx.x * 4 + (tid >> 6);
    int c = wg & 31, dg = (wg >> 5) & 31, b = wg >> 10;
    int d = dg * 4 + dloc;
    float Ads = -__expf(A_log[d * DSx + s]);
    float4 w4 = *(const float4*)(dtw + d * 4);
    float dbias = dtbias[d];
    int chain = (b * DIx + d) * DSx + s;
    float h = Hin[(size_t)c * 16384 + chain];
    float Dv = Dssm[d];
    int t0 = c * CLEN;
    for (int t = t0; t < t0 + CLEN; ++t) {
        size_t row = (size_t)b * LL + t;
        float4 di = *(const float4*)(dbl + row * 64);
        float dtv = di.x*w4.x + di.y*w4.y + di.z*w4.z + di.w*w4.w + dbias;
        dtv = (dtv > 15.f) ? dtv : __logf(1.f + __expf(dtv));
        float xv = xs[row * 128 + d];
        float Bv = dbl[row * 64 + 4 + s];
        float Cv = dbl[row * 64 + 20 + s];
        float da = __expf(dtv * Ads);
        h = da * h + dtv * Bv * xv;
        float part = h * Cv;
        part += __shfl_xor(part, 1);
        part += __shfl_xor(part, 2);
        part += __shfl_xor(part, 4);
        part += __shfl_xor(part, 8);
        if (s == 0) {
            float y = part + xv * Dv;
            float zv = xz[row * 256 + 128 + d];
            y *= zv / (1.f + __expf(-zv));
            ym[row * 128 + d] = y;
        }
    }
}

// ---------------------------------------------------------------
// BN partial sums: block (c,b) reduces 4096 contiguous floats,
// atomicAdd into stats[c] (sum) and stats[64+c] (sumsq).
// ---------------------------------------------------------------
__global__ __launch_bounds__(256) void k_bnpart(const float* __restrict__ xm,
        float* __restrict__ stats) {
    int c = blockIdx.x >> 3, b = blockIdx.x & 7;
    const float* p = xm + ((size_t)b * DD + c) * LL;
    int tid = threadIdx.x;
    float s = 0.f, ss = 0.f;
#pragma unroll
    for (int it = 0; it < 4; ++it) {
        float4 v = *(const float4*)(p + (size_t)(it * 256 + tid) * 4);
        s  += v.x + v.y + v.z + v.w;
        ss += v.x*v.x + v.y*v.y + v.z*v.z + v.w*v.w;
    }
    for (int o = 32; o > 0; o >>= 1) {
        s  += __shfl_down(s, o);
        ss += __shfl_down(ss, o);
    }
    __shared__ float red[8];
    int wid = tid >> 6;
    if ((tid & 63) == 0) { red[wid] = s; red[4 + wid] = ss; }
    __syncthreads();
    if (tid == 0) {
        atomicAdd(&stats[c], red[0] + red[1] + red[2] + red[3]);
        atomicAdd(&stats[64 + c], red[4] + red[5] + red[6] + red[7]);
    }
}

// ---------------------------------------------------------------
// BN apply + residual: xfinal = (xmerge-mean)*rstd*g + b + x_in
// ---------------------------------------------------------------
__global__ __launch_bounds__(256) void k_bnapply(const float* __restrict__ xm,
        const float* __restrict__ stats, const float* __restrict__ gamma,
        const float* __restrict__ beta, const float* __restrict__ xin,
        float* __restrict__ out) {
    int i = blockIdx.x * 256 + threadIdx.x;     // B*64*L/4
    size_t f = (size_t)i * 4;
    int c = (int)((f / LL) & 63);
    const float inv = 1.f / (float)(BB * LL);
    float mean = stats[c] * inv;
    float var  = stats[64 + c] * inv - mean * mean;
    float rstd = rsqrtf(var + 1e-5f);
    float4 v = *(const float4*)(xm + f);
    float4 r = *(const float4*)(xin + f);
    float g = gamma[c] * rstd;
    float sh = beta[c] - mean * g;
    v.x = v.x * g + sh + r.x;
    v.y = v.y * g + sh + r.y;
    v.z = v.z * g + sh + r.z;
    v.w = v.w * g + sh + r.w;
    *(float4*)(out + f) = v;
}

// ---------------------------------------------------------------
// PixelShuffle(r=10) + linear upsample of x + add -> d_out
// ---------------------------------------------------------------
__global__ __launch_bounds__(256) void k_final(const float* __restrict__ xp,
        const float* __restrict__ x, float* __restrict__ out) {
    int i = blockIdx.x * 256 + threadIdx.x;     // B*12*OUTL
    int j = i % OUTL;
    int c = (i / OUTL) % 12;
    int b = i / (OUTL * 12);
    int r = j % RR, l = j / RR;
    float ps = xp[((size_t)b * 120 + r * 12 + c) * LL + l];
    float src = ((float)j + 0.5f) * 0.1f - 0.5f;
    src = fmaxf(src, 0.f);
    int i0 = (int)src;
    if (i0 > LL - 1) i0 = LL - 1;
    int i1 = (i0 + 1 < LL) ? i0 + 1 : LL - 1;
    float frac = src - (float)i0;
    const float* xr = x + ((size_t)b * 12 + c) * LL;
    float up = xr[i0] * (1.f - frac) + xr[i1] * frac;
    out[i] = ps + up;
}

// ---------------------------------------------------------------
extern "C" void kernel_launch(void* const* d_in, const int* in_sizes, int n_in,
                              void* d_out, int out_size, void* d_ws, size_t ws_size,
                              hipStream_t stream) {
    const float* x          = (const float*)d_in[0];
    const float* conv_in_w  = (const float*)d_in[1];
    const float* conv_in_b  = (const float*)d_in[2];
    const float* in_proj_w  = (const float*)d_in[3];
    const float* dw_w       = (const float*)d_in[4];
    const float* dw_b       = (const float*)d_in[5];
    const float* x_proj_w   = (const float*)d_in[6];
    const float* dt_w       = (const float*)d_in[7];
    const float* dt_b       = (const float*)d_in[8];
    const float* A_log      = (const float*)d_in[9];
    const float* Dssm       = (const float*)d_in[10];
    const float* out_proj_w = (const float*)d_in[11];
    const float* cm_w       = (const float*)d_in[12];
    const float* cm_b       = (const float*)d_in[13];
    const float* bn_g       = (const float*)d_in[14];
    const float* bn_be      = (const float*)d_in[15];
    const float* ps_w       = (const float*)d_in[16];
    const float* ps_b       = (const float*)d_in[17];

    float* ws = (float*)d_ws;
    float* xin_bdl = ws;                    //  2,097,152
    float* xz      = ws + 2097152;          //  8,388,608
    float* xs_act  = ws + 10485760;         //  4,194,304
    float* dbl64   = ws + 14680064;         //  2,097,152
    float* P       = ws + 16777216;         //    524,288
    float* Q       = ws + 17301504;         //    524,288
    float* Hin     = ws + 17825792;         //    524,288
    float* ym      = ws + 18350080;         //  4,194,304
    float* xm_bdl  = ws + 22544384;         //  2,097,152
    float* xmerge  = ws + 24641536;         //  2,097,152
    float* stats   = ws + 26738688;         //        128
    // aliases (sources dead after scan phase 3)
    float* xfinal  = xs_act;
    float* xp      = xz;

    k_conv<CIN, 64, 2, true><<<1024, 256, 0, stream>>>(x, conv_in_w, conv_in_b, xin_bdl);
    k_gemm_inproj<<<512, 256, 0, stream>>>(xin_bdl, in_proj_w, xz);
    k_dwconv<<<16384, 256, 0, stream>>>(xz, dw_w, dw_b, xs_act);
    k_gemm64<36, true><<<256, 256, 0, stream>>>(xs_act, x_proj_w, dbl64);
    k_scan1<<<2048, 256, 0, stream>>>(xs_act, dbl64, dt_w, dt_b, A_log, P, Q);
    k_scan2<<<64, 256, 0, stream>>>(P, Q, Hin, stats);
    k_scan3<<<2048, 256, 0, stream>>>(xs_act, dbl64, dt_w, dt_b, A_log, Hin, xz, Dssm, ym);
    k_gemm64_tr<<<256, 256, 0, stream>>>(ym, out_proj_w, xin_bdl, xm_bdl);
    k_conv<64, 64, 2, false><<<1024, 256, 0, stream>>>(xm_bdl, cm_w, cm_b, xmerge);
    k_bnpart<<<512, 256, 0, stream>>>(xmerge, stats);
    k_bnapply<<<2048, 256, 0, stream>>>(xmerge, stats, bn_g, bn_be, xin_bdl, xfinal);
    k_conv<64, 120, 2, false><<<1920, 256, 0, stream>>>(xfinal, ps_w, ps_b, xp);
    k_final<<<15360, 256, 0, stream>>>(xp, x, (float*)d_out);
}

// Round 5
// 558.963 us; speedup vs baseline: 1.0782x; 1.0782x over previous
//
#include <hip/hip_runtime.h>
#include <math.h>

#define BB 8
#define CIN 12
#define LL 4096
#define DD 64
#define DIx 128
#define DSx 16
#define RR 10
#define KK 15
#define NCH 32      // scan chunks
#define CLEN 128    // LL/NCH
#define OUTL 40960  // LL*RR

// ---------------------------------------------------------------
// Direct conv1d, K=15, pad 7. Each thread: 4 consecutive l, COT co's.
// ---------------------------------------------------------------
template<int CI, int CO, int COT, bool LEAKY>
__global__ __launch_bounds__(256) void k_conv(const float* __restrict__ in,
        const float* __restrict__ w, const float* __restrict__ bias,
        float* __restrict__ out) {
    const int LT = 1024;
    int tid = threadIdx.x;
    int bid = blockIdx.x;
    const int nlt = LL / LT;        // 4
    const int ncog = CO / COT;
    int lt = bid % nlt;
    int cog = (bid / nlt) % ncog;
    int b = bid / (nlt * ncog);
    int l0 = lt * LT + tid * 4;
    int co0 = cog * COT;

    float acc[COT][4];
#pragma unroll
    for (int c = 0; c < COT; ++c) {
        float bv = bias[co0 + c];
#pragma unroll
        for (int j = 0; j < 4; ++j) acc[c][j] = bv;
    }

    for (int ci = 0; ci < CI; ++ci) {
        const float* inp = in + ((size_t)b * CI + ci) * LL;
        float in20[20];
#pragma unroll
        for (int q = 0; q < 5; ++q) {
            int gi = l0 - 8 + q * 4;
            if (gi >= 0 && gi + 3 < LL) {
                float4 v = *(const float4*)(inp + gi);
                in20[q*4+0] = v.x; in20[q*4+1] = v.y;
                in20[q*4+2] = v.z; in20[q*4+3] = v.w;
            } else {
#pragma unroll
                for (int j = 0; j < 4; ++j) {
                    int g = gi + j;
                    in20[q*4+j] = (g >= 0 && g < LL) ? inp[g] : 0.f;
                }
            }
        }
#pragma unroll
        for (int c = 0; c < COT; ++c) {
            const float* wp = w + ((size_t)(co0 + c) * CI + ci) * KK;
#pragma unroll
            for (int k = 0; k < KK; ++k) {
                float wv = wp[k];
#pragma unroll
                for (int j = 0; j < 4; ++j)
                    acc[c][j] += wv * in20[j + k + 1];
            }
        }
    }
#pragma unroll
    for (int c = 0; c < COT; ++c) {
        float r[4];
#pragma unroll
        for (int j = 0; j < 4; ++j) {
            float v = acc[c][j];
            if (LEAKY) v = (v >= 0.f) ? v : 0.01f * v;
            r[j] = v;
        }
        float4 v4 = make_float4(r[0], r[1], r[2], r[3]);
        *(float4*)(out + ((size_t)b * CO + co0 + c) * LL + l0) = v4;
    }
}

// ---------------------------------------------------------------
// in_proj GEMM: C(32768,256) = A^T-view * W(256,64)^T
// A read directly from (B,64,L) layout (coalesced along l).
// ---------------------------------------------------------------
__global__ __launch_bounds__(256) void k_gemm_inproj(const float* __restrict__ A,
        const float* __restrict__ W, float* __restrict__ C) {
    __shared__ float At[64 * 132];
    __shared__ float Wt[64 * 132];
    int tid = threadIdx.x;
    int bid = blockIdx.x;
    int nb = bid & 1;
    int mb = bid >> 1;
    int row0 = mb * 128;
    int n0 = nb * 128;
    int b = row0 >> 12;
    int l0 = row0 & 4095;
#pragma unroll
    for (int it = 0; it < 8; ++it) {
        int idx = it * 256 + tid;
        int k = idx >> 5, m4 = (idx & 31) * 4;
        float4 v = *(const float4*)(A + ((size_t)b * DD + k) * LL + l0 + m4);
        *(float4*)&At[k * 132 + m4] = v;
    }
#pragma unroll
    for (int it = 0; it < 8; ++it) {
        int lin = it * 1024 + tid * 4;
        int n = lin >> 6, k = lin & 63;
        float4 v = *(const float4*)(W + (size_t)(n0 + n) * 64 + k);
        Wt[(k+0)*132 + n] = v.x; Wt[(k+1)*132 + n] = v.y;
        Wt[(k+2)*132 + n] = v.z; Wt[(k+3)*132 + n] = v.w;
    }
    __syncthreads();
    int tx = tid & 15, ty = tid >> 4;
    float acc[2][2][4][4] = {};
#pragma unroll 4
    for (int k = 0; k < 64; ++k) {
        float4 aLo = *(float4*)&At[k*132 + ty*4];
        float4 aHi = *(float4*)&At[k*132 + 64 + ty*4];
        float4 bLo = *(float4*)&Wt[k*132 + tx*4];
        float4 bHi = *(float4*)&Wt[k*132 + 64 + tx*4];
        float a0[4] = {aLo.x, aLo.y, aLo.z, aLo.w};
        float a1[4] = {aHi.x, aHi.y, aHi.z, aHi.w};
        float b0[4] = {bLo.x, bLo.y, bLo.z, bLo.w};
        float b1[4] = {bHi.x, bHi.y, bHi.z, bHi.w};
#pragma unroll
        for (int mm = 0; mm < 4; ++mm)
#pragma unroll
            for (int nn = 0; nn < 4; ++nn) {
                acc[0][0][mm][nn] += a0[mm] * b0[nn];
                acc[0][1][mm][nn] += a0[mm] * b1[nn];
                acc[1][0][mm][nn] += a1[mm] * b0[nn];
                acc[1][1][mm][nn] += a1[mm] * b1[nn];
            }
    }
#pragma unroll
    for (int qm = 0; qm < 2; ++qm)
#pragma unroll
        for (int mm = 0; mm < 4; ++mm) {
            int row = row0 + qm*64 + ty*4 + mm;
#pragma unroll
            for (int qn = 0; qn < 2; ++qn) {
                float4 v = make_float4(acc[qm][qn][mm][0], acc[qm][qn][mm][1],
                                       acc[qm][qn][mm][2], acc[qm][qn][mm][3]);
                *(float4*)(C + (size_t)row * 256 + n0 + qn*64 + tx*4) = v;
            }
        }
}

// ---------------------------------------------------------------
// x_proj GEMM: dbl(32768,64) = A(32768,128) * W(36,128)^T (zero-padded)
// ---------------------------------------------------------------
template<int NW, bool GUARD>
__global__ __launch_bounds__(256) void k_gemm64(const float* __restrict__ A,
        const float* __restrict__ W, float* __restrict__ out) {
    __shared__ float At[64 * 132];
    __shared__ float Wt[64 * 68];
    int tid = threadIdx.x;
    int row0 = blockIdx.x * 128;
    int tx = tid & 15, ty = tid >> 4;
    float acc[2][4][4] = {};
#pragma unroll
    for (int kt = 0; kt < 2; ++kt) {
        __syncthreads();
#pragma unroll
        for (int it = 0; it < 8; ++it) {
            int lin = it * 1024 + tid * 4;
            int m = lin >> 6, k = lin & 63;
            float4 v = *(const float4*)(A + (size_t)(row0 + m) * 128 + kt*64 + k);
            At[(k+0)*132 + m] = v.x; At[(k+1)*132 + m] = v.y;
            At[(k+2)*132 + m] = v.z; At[(k+3)*132 + m] = v.w;
        }
#pragma unroll
        for (int it = 0; it < 4; ++it) {
            int lin = it * 1024 + tid * 4;
            int n = lin >> 6, k = lin & 63;
            float4 v = make_float4(0.f, 0.f, 0.f, 0.f);
            if (!GUARD || n < NW)
                v = *(const float4*)(W + (size_t)n * 128 + kt*64 + k);
            Wt[(k+0)*68 + n] = v.x; Wt[(k+1)*68 + n] = v.y;
            Wt[(k+2)*68 + n] = v.z; Wt[(k+3)*68 + n] = v.w;
        }
        __syncthreads();
#pragma unroll 4
        for (int k = 0; k < 64; ++k) {
            float4 aLo = *(float4*)&At[k*132 + ty*4];
            float4 aHi = *(float4*)&At[k*132 + 64 + ty*4];
            float4 b4  = *(float4*)&Wt[k*68 + tx*4];
            float a0[4] = {aLo.x, aLo.y, aLo.z, aLo.w};
            float a1[4] = {aHi.x, aHi.y, aHi.z, aHi.w};
            float bv[4] = {b4.x, b4.y, b4.z, b4.w};
#pragma unroll
            for (int mm = 0; mm < 4; ++mm)
#pragma unroll
                for (int nn = 0; nn < 4; ++nn) {
                    acc[0][mm][nn] += a0[mm] * bv[nn];
                    acc[1][mm][nn] += a1[mm] * bv[nn];
                }
        }
    }
#pragma unroll
    for (int qm = 0; qm < 2; ++qm)
#pragma unroll
        for (int mm = 0; mm < 4; ++mm) {
            int row = row0 + qm*64 + ty*4 + mm;
            float4 v = make_float4(acc[qm][mm][0], acc[qm][mm][1],
                                   acc[qm][mm][2], acc[qm][mm][3]);
            *(float4*)(out + (size_t)row * 64 + tx*4) = v;
        }
}

// ---------------------------------------------------------------
// out_proj GEMM + residual + transposed write to (B,64,L).
// ---------------------------------------------------------------
__global__ __launch_bounds__(256) void k_gemm64_tr(const float* __restrict__ A,
        const float* __restrict__ W, const float* __restrict__ res,
        float* __restrict__ out) {
    __shared__ float smem[64*132 + 64*68];   // 12800 floats
    float* At = smem;
    float* Wt = smem + 64*132;
    int tid = threadIdx.x;
    int row0 = blockIdx.x * 128;
    int tx = tid & 15, ty = tid >> 4;
    float acc[2][4][4] = {};
#pragma unroll
    for (int kt = 0; kt < 2; ++kt) {
        __syncthreads();
#pragma unroll
        for (int it = 0; it < 8; ++it) {
            int lin = it * 1024 + tid * 4;
            int m = lin >> 6, k = lin & 63;
            float4 v = *(const float4*)(A + (size_t)(row0 + m) * 128 + kt*64 + k);
            At[(k+0)*132 + m] = v.x; At[(k+1)*132 + m] = v.y;
            At[(k+2)*132 + m] = v.z; At[(k+3)*132 + m] = v.w;
        }
#pragma unroll
        for (int it = 0; it < 4; ++it) {
            int lin = it * 1024 + tid * 4;
            int n = lin >> 6, k = lin & 63;
            float4 v = *(const float4*)(W + (size_t)n * 128 + kt*64 + k);
            Wt[(k+0)*68 + n] = v.x; Wt[(k+1)*68 + n] = v.y;
            Wt[(k+2)*68 + n] = v.z; Wt[(k+3)*68 + n] = v.w;
        }
        __syncthreads();
#pragma unroll 4
        for (int k = 0; k < 64; ++k) {
            float4 aLo = *(float4*)&At[k*132 + ty*4];
            float4 aHi = *(float4*)&At[k*132 + 64 + ty*4];
            float4 b4  = *(float4*)&Wt[k*68 + tx*4];
            float a0[4] = {aLo.x, aLo.y, aLo.z, aLo.w};
            float a1[4] = {aHi.x, aHi.y, aHi.z, aHi.w};
            float bv[4] = {b4.x, b4.y, b4.z, b4.w};
#pragma unroll
            for (int mm = 0; mm < 4; ++mm)
#pragma unroll
                for (int nn = 0; nn < 4; ++nn) {
                    acc[0][mm][nn] += a0[mm] * bv[nn];
                    acc[1][mm][nn] += a1[mm] * bv[nn];
                }
        }
    }
    __syncthreads();
    float* tile = smem;   // 128*68 = 8704 <= 12800
#pragma unroll
    for (int qm = 0; qm < 2; ++qm)
#pragma unroll
        for (int mm = 0; mm < 4; ++mm) {
            int lrow = qm*64 + ty*4 + mm;
            *(float4*)&tile[lrow*68 + tx*4] = make_float4(
                acc[qm][mm][0], acc[qm][mm][1], acc[qm][mm][2], acc[qm][mm][3]);
        }
    __syncthreads();
    int b = row0 >> 12, l0 = row0 & 4095;
#pragma unroll
    for (int it = 0; it < 8; ++it) {
        int idx = it * 256 + tid;
        int d = idx >> 5, l4 = (idx & 31) * 4;
        size_t base = ((size_t)b * DD + d) * LL + l0 + l4;
        float4 r = *(const float4*)(res + base);
        float4 o;
        o.x = tile[(l4+0)*68 + d] + r.x;
        o.y = tile[(l4+1)*68 + d] + r.y;
        o.z = tile[(l4+2)*68 + d] + r.z;
        o.w = tile[(l4+3)*68 + d] + r.w;
        *(float4*)(out + base) = o;
    }
}

// ---------------------------------------------------------------
// Depthwise causal conv (DC=4) + silu.
// ---------------------------------------------------------------
__global__ __launch_bounds__(256) void k_dwconv(const float* __restrict__ xz,
        const float* __restrict__ w, const float* __restrict__ bias,
        float* __restrict__ xs_act) {
    int idx = blockIdx.x * 256 + threadIdx.x;   // B*L*128
    int d = idx & 127;
    int row = idx >> 7;                          // b*L + l
    int l = row & (LL - 1);
    float s = bias[d];
    const float* wp = w + d * 4;
#pragma unroll
    for (int j = 0; j < 4; ++j) {
        int li = l - 3 + j;
        if (li >= 0) s += xz[(size_t)(row - 3 + j) * 256 + d] * wp[j];
    }
    float sg = 1.f / (1.f + __expf(-s));
    xs_act[idx] = s * sg;
}

// ---------------------------------------------------------------
// dt = softplus(dbl[:, :4] @ dt_proj_w^T + b)  (separate pass: scans
// would recompute it 16x per s-lane otherwise)
// ---------------------------------------------------------------
__global__ __launch_bounds__(256) void k_dtproj(const float* __restrict__ dbl,
        const float* __restrict__ w, const float* __restrict__ bias,
        float* __restrict__ dt) {
    int idx = blockIdx.x * 256 + threadIdx.x;   // B*L*128
    int d = idx & 127;
    int row = idx >> 7;
    float4 di = *(const float4*)(dbl + (size_t)row * 64);
    float4 w4 = *(const float4*)(w + d * 4);
    float v = di.x*w4.x + di.y*w4.y + di.z*w4.z + di.w*w4.w + bias[d];
    dt[idx] = (v > 15.f) ? v : log1pf(__expf(v));
}

// ---------------------------------------------------------------
// Scan phase 1: per (b,d,s,chunk) P=prod(dA), Q=h(end|h0=0).
// Lean inner loop: 1 exp + 3 FMA/mul per t; imm-offset loads (unroll 8).
// ---------------------------------------------------------------
__global__ __launch_bounds__(256) void k_scan1(const float* __restrict__ dt,
        const float* __restrict__ xs, const float* __restrict__ dbl,
        const float* __restrict__ A_log, float* __restrict__ P,
        float* __restrict__ Q) {
    int tid = threadIdx.x, lane = tid & 63;
    int s = lane & 15, dloc = lane >> 4;
    int wg = blockIdx.x * 4 + (tid >> 6);
    int c = wg & 31, dg = (wg >> 5) & 31, b = wg >> 10;
    int d = dg * 4 + dloc;
    float Ads = -__expf(A_log[d * DSx + s]);
    size_t base = (size_t)b * LL + (size_t)c * CLEN;
    const float* pdt = dt + base * 128 + d;
    const float* pxs = xs + base * 128 + d;
    const float* pB  = dbl + base * 64 + 4 + s;
    float h = 0.f, p = 1.f;
    for (int t = 0; t < CLEN; t += 8) {
#pragma unroll
        for (int u = 0; u < 8; ++u) {
            float dtv = pdt[u * 128];
            float xv  = pxs[u * 128];
            float Bv  = pB[u * 64];
            float da  = __expf(dtv * Ads);
            h = da * h + dtv * xv * Bv;
            p *= da;
        }
        pdt += 1024; pxs += 1024; pB += 512;
    }
    int chain = (b * DIx + d) * DSx + s;
    P[(size_t)c * 16384 + chain] = p;
    Q[(size_t)c * 16384 + chain] = h;
}

// ---------------------------------------------------------------
// Scan phase 2: sequential prefix over chunks + zero BN stats accum.
// ---------------------------------------------------------------
__global__ __launch_bounds__(256) void k_scan2(const float* __restrict__ P,
        const float* __restrict__ Q, float* __restrict__ Hin,
        float* __restrict__ stats) {
    int chain = blockIdx.x * 256 + threadIdx.x;  // 16384
    if (blockIdx.x == 0 && threadIdx.x < 128) stats[threadIdx.x] = 0.f;
    float carry = 0.f;
    for (int c = 0; c < NCH; ++c) {
        Hin[(size_t)c * 16384 + chain] = carry;
        carry = P[(size_t)c * 16384 + chain] * carry + Q[(size_t)c * 16384 + chain];
    }
}

// ---------------------------------------------------------------
// Scan phase 3: recompute with h_in, emit y (+xs*D, *silu(z)).
// ---------------------------------------------------------------
__global__ __launch_bounds__(256) void k_scan3(const float* __restrict__ dt,
        const float* __restrict__ xs, const float* __restrict__ dbl,
        const float* __restrict__ A_log, const float* __restrict__ Hin,
        const float* __restrict__ xz, const float* __restrict__ Dssm,
        float* __restrict__ ym) {
    int tid = threadIdx.x, lane = tid & 63;
    int s = lane & 15, dloc = lane >> 4;
    int wg = blockIdx.x * 4 + (tid >> 6);
    int c = wg & 31, dg = (wg >> 5) & 31, b = wg >> 10;
    int d = dg * 4 + dloc;
    float Ads = -__expf(A_log[d * DSx + s]);
    int chain = (b * DIx + d) * DSx + s;
    float h = Hin[(size_t)c * 16384 + chain];
    float Dv = Dssm[d];
    size_t base = (size_t)b * LL + (size_t)c * CLEN;
    const float* pdt = dt + base * 128 + d;
    const float* pxs = xs + base * 128 + d;
    const float* pB  = dbl + base * 64 + 4 + s;
    const float* pC  = dbl + base * 64 + 20 + s;
    const float* pz  = xz + base * 256 + 128 + d;
    float* pym = ym + base * 128 + d;
    for (int t = 0; t < CLEN; t += 8) {
#pragma unroll
        for (int u = 0; u < 8; ++u) {
            float dtv = pdt[u * 128];
            float xv  = pxs[u * 128];
            float Bv  = pB[u * 64];
            float Cv  = pC[u * 64];
            float da  = __expf(dtv * Ads);
            h = da * h + dtv * xv * Bv;
            float part = h * Cv;
            part += __shfl_xor(part, 1);
            part += __shfl_xor(part, 2);
            part += __shfl_xor(part, 4);
            part += __shfl_xor(part, 8);
            if (s == 0) {
                float y = part + xv * Dv;
                float zv = pz[u * 256];
                y *= zv / (1.f + __expf(-zv));
                pym[u * 128] = y;
            }
        }
        pdt += 1024; pxs += 1024; pB += 512; pC += 512; pz += 2048; pym += 1024;
    }
}

// ---------------------------------------------------------------
// BN partial sums: block (c,b) -> atomicAdd into stats.
// ---------------------------------------------------------------
__global__ __launch_bounds__(256) void k_bnpart(const float* __restrict__ xm,
        float* __restrict__ stats) {
    int c = blockIdx.x >> 3, b = blockIdx.x & 7;
    const float* p = xm + ((size_t)b * DD + c) * LL;
    int tid = threadIdx.x;
    float s = 0.f, ss = 0.f;
#pragma unroll
    for (int it = 0; it < 4; ++it) {
        float4 v = *(const float4*)(p + (size_t)(it * 256 + tid) * 4);
        s  += v.x + v.y + v.z + v.w;
        ss += v.x*v.x + v.y*v.y + v.z*v.z + v.w*v.w;
    }
    for (int o = 32; o > 0; o >>= 1) {
        s  += __shfl_down(s, o);
        ss += __shfl_down(ss, o);
    }
    __shared__ float red[8];
    int wid = tid >> 6;
    if ((tid & 63) == 0) { red[wid] = s; red[4 + wid] = ss; }
    __syncthreads();
    if (tid == 0) {
        atomicAdd(&stats[c], red[0] + red[1] + red[2] + red[3]);
        atomicAdd(&stats[64 + c], red[4] + red[5] + red[6] + red[7]);
    }
}

// ---------------------------------------------------------------
// BN apply + residual.
// ---------------------------------------------------------------
__global__ __launch_bounds__(256) void k_bnapply(const float* __restrict__ xm,
        const float* __restrict__ stats, const float* __restrict__ gamma,
        const float* __restrict__ beta, const float* __restrict__ xin,
        float* __restrict__ out) {
    int i = blockIdx.x * 256 + threadIdx.x;     // B*64*L/4
    size_t f = (size_t)i * 4;
    int c = (int)((f / LL) & 63);
    const float inv = 1.f / (float)(BB * LL);
    float mean = stats[c] * inv;
    float var  = stats[64 + c] * inv - mean * mean;
    float rstd = rsqrtf(var + 1e-5f);
    float4 v = *(const float4*)(xm + f);
    float4 r = *(const float4*)(xin + f);
    float g = gamma[c] * rstd;
    float sh = beta[c] - mean * g;
    v.x = v.x * g + sh + r.x;
    v.y = v.y * g + sh + r.y;
    v.z = v.z * g + sh + r.z;
    v.w = v.w * g + sh + r.w;
    *(float4*)(out + f) = v;
}

// ---------------------------------------------------------------
// PixelShuffle(r=10) + linear upsample of x + add -> d_out
// ---------------------------------------------------------------
__global__ __launch_bounds__(256) void k_final(const float* __restrict__ xp,
        const float* __restrict__ x, float* __restrict__ out) {
    int i = blockIdx.x * 256 + threadIdx.x;     // B*12*OUTL
    int j = i % OUTL;
    int c = (i / OUTL) % 12;
    int b = i / (OUTL * 12);
    int r = j % RR, l = j / RR;
    float ps = xp[((size_t)b * 120 + r * 12 + c) * LL + l];
    float src = ((float)j + 0.5f) * 0.1f - 0.5f;
    src = fmaxf(src, 0.f);
    int i0 = (int)src;
    if (i0 > LL - 1) i0 = LL - 1;
    int i1 = (i0 + 1 < LL) ? i0 + 1 : LL - 1;
    float frac = src - (float)i0;
    const float* xr = x + ((size_t)b * 12 + c) * LL;
    float up = xr[i0] * (1.f - frac) + xr[i1] * frac;
    out[i] = ps + up;
}

// ---------------------------------------------------------------
extern "C" void kernel_launch(void* const* d_in, const int* in_sizes, int n_in,
                              void* d_out, int out_size, void* d_ws, size_t ws_size,
                              hipStream_t stream) {
    const float* x          = (const float*)d_in[0];
    const float* conv_in_w  = (const float*)d_in[1];
    const float* conv_in_b  = (const float*)d_in[2];
    const float* in_proj_w  = (const float*)d_in[3];
    const float* dw_w       = (const float*)d_in[4];
    const float* dw_b       = (const float*)d_in[5];
    const float* x_proj_w   = (const float*)d_in[6];
    const float* dt_w       = (const float*)d_in[7];
    const float* dt_b       = (const float*)d_in[8];
    const float* A_log      = (const float*)d_in[9];
    const float* Dssm       = (const float*)d_in[10];
    const float* out_proj_w = (const float*)d_in[11];
    const float* cm_w       = (const float*)d_in[12];
    const float* cm_b       = (const float*)d_in[13];
    const float* bn_g       = (const float*)d_in[14];
    const float* bn_be      = (const float*)d_in[15];
    const float* ps_w       = (const float*)d_in[16];
    const float* ps_b       = (const float*)d_in[17];

    float* ws = (float*)d_ws;
    float* xin_bdl = ws;                    //  2,097,152
    float* xz      = ws + 2097152;          //  8,388,608
    float* xs_act  = ws + 10485760;         //  4,194,304
    float* dbl64   = ws + 14680064;         //  2,097,152
    float* P       = ws + 16777216;         //    524,288
    float* Q       = ws + 17301504;         //    524,288
    float* Hin     = ws + 17825792;         //    524,288
    float* ym      = ws + 18350080;         //  4,194,304
    float* xm_bdl  = ws + 22544384;         //  2,097,152
    float* xmerge  = ws + 24641536;         //  2,097,152
    float* stats   = ws + 26738688;         //        128
    float* dtb     = ws + 26738816;         //  4,194,304  (end 30,933,120)
    // aliases (sources dead after scan phase 3)
    float* xfinal  = xs_act;
    float* xp      = xz;

    k_conv<CIN, 64, 2, true><<<1024, 256, 0, stream>>>(x, conv_in_w, conv_in_b, xin_bdl);
    k_gemm_inproj<<<512, 256, 0, stream>>>(xin_bdl, in_proj_w, xz);
    k_dwconv<<<16384, 256, 0, stream>>>(xz, dw_w, dw_b, xs_act);
    k_gemm64<36, true><<<256, 256, 0, stream>>>(xs_act, x_proj_w, dbl64);
    k_dtproj<<<16384, 256, 0, stream>>>(dbl64, dt_w, dt_b, dtb);
    k_scan1<<<2048, 256, 0, stream>>>(dtb, xs_act, dbl64, A_log, P, Q);
    k_scan2<<<64, 256, 0, stream>>>(P, Q, Hin, stats);
    k_scan3<<<2048, 256, 0, stream>>>(dtb, xs_act, dbl64, A_log, Hin, xz, Dssm, ym);
    k_gemm64_tr<<<256, 256, 0, stream>>>(ym, out_proj_w, xin_bdl, xm_bdl);
    k_conv<64, 64, 2, false><<<1024, 256, 0, stream>>>(xm_bdl, cm_w, cm_b, xmerge);
    k_bnpart<<<512, 256, 0, stream>>>(xmerge, stats);
    k_bnapply<<<2048, 256, 0, stream>>>(xmerge, stats, bn_g, bn_be, xin_bdl, xfinal);
    k_conv<64, 120, 2, false><<<1920, 256, 0, stream>>>(xfinal, ps_w, ps_b, xp);
    k_final<<<15360, 256, 0, stream>>>(xp, x, (float*)d_out);
}

// Round 6
// 400.561 us; speedup vs baseline: 1.5045x; 1.3955x over previous
//
#include <hip/hip_runtime.h>
#include <math.h>

#define BB 8
#define CIN 12
#define LL 4096
#define DD 64
#define DIx 128
#define DSx 16
#define RR 10
#define KK 15
#define NCH 32      // scan chunks
#define CLEN 128    // LL/NCH
#define OUTL 40960  // LL*RR

typedef __attribute__((ext_vector_type(8))) short s8v;
typedef __attribute__((ext_vector_type(8))) __bf16 b8v;
typedef __attribute__((ext_vector_type(4))) float f4v;
union frag_u { s8v s; b8v b; };

__device__ __forceinline__ unsigned short f2b(float f) {
    unsigned int u = __float_as_uint(f);
    u = (u + 0x7fffu + ((u >> 16) & 1u)) >> 16;
    return (unsigned short)u;
}
__device__ __forceinline__ float b2f(unsigned short h) {
    return __uint_as_float(((unsigned int)h) << 16);
}

// ---------------------------------------------------------------
// Direct conv1d fp32 (kept for conv_in, CI=12 only).
// ---------------------------------------------------------------
template<int CI, int CO, int COT, bool LEAKY>
__global__ __launch_bounds__(256) void k_conv(const float* __restrict__ in,
        const float* __restrict__ w, const float* __restrict__ bias,
        float* __restrict__ out) {
    const int LT = 1024;
    int tid = threadIdx.x;
    int bid = blockIdx.x;
    const int nlt = LL / LT;        // 4
    const int ncog = CO / COT;
    int lt = bid % nlt;
    int cog = (bid / nlt) % ncog;
    int b = bid / (nlt * ncog);
    int l0 = lt * LT + tid * 4;
    int co0 = cog * COT;

    float acc[COT][4];
#pragma unroll
    for (int c = 0; c < COT; ++c) {
        float bv = bias[co0 + c];
#pragma unroll
        for (int j = 0; j < 4; ++j) acc[c][j] = bv;
    }
    for (int ci = 0; ci < CI; ++ci) {
        const float* inp = in + ((size_t)b * CI + ci) * LL;
        float in20[20];
#pragma unroll
        for (int q = 0; q < 5; ++q) {
            int gi = l0 - 8 + q * 4;
            if (gi >= 0 && gi + 3 < LL) {
                float4 v = *(const float4*)(inp + gi);
                in20[q*4+0] = v.x; in20[q*4+1] = v.y;
                in20[q*4+2] = v.z; in20[q*4+3] = v.w;
            } else {
#pragma unroll
                for (int j = 0; j < 4; ++j) {
                    int g = gi + j;
                    in20[q*4+j] = (g >= 0 && g < LL) ? inp[g] : 0.f;
                }
            }
        }
#pragma unroll
        for (int c = 0; c < COT; ++c) {
            const float* wp = w + ((size_t)(co0 + c) * CI + ci) * KK;
#pragma unroll
            for (int k = 0; k < KK; ++k) {
                float wv = wp[k];
#pragma unroll
                for (int j = 0; j < 4; ++j)
                    acc[c][j] += wv * in20[j + k + 1];
            }
        }
    }
#pragma unroll
    for (int c = 0; c < COT; ++c) {
        float r[4];
#pragma unroll
        for (int j = 0; j < 4; ++j) {
            float v = acc[c][j];
            if (LEAKY) v = (v >= 0.f) ? v : 0.01f * v;
            r[j] = v;
        }
        *(float4*)(out + ((size_t)b * CO + co0 + c) * LL + l0) =
            make_float4(r[0], r[1], r[2], r[3]);
    }
}

// ---------------------------------------------------------------
// Weight prep: frag-linear bf16 for MFMA A-operand (M=co rows).
// wp[(((k*NCOB+cob)*2+cis)*64+lane)*8+j] = w[co][ci][k],
// co = cob*16 + (lane&15), ci = cis*32 + (lane>>4)*8 + j.
// ---------------------------------------------------------------
template<int CO_REAL, int NCOB>
__global__ __launch_bounds__(256) void k_wprep(const float* __restrict__ w,
        unsigned short* __restrict__ wp) {
    int idx = blockIdx.x * 256 + threadIdx.x;
    if (idx >= 15 * NCOB * 1024) return;
    int j = idx & 7;
    int lane = (idx >> 3) & 63;
    int cis = (idx >> 9) & 1;
    int rest = idx >> 10;
    int cob = rest % NCOB;
    int kk = rest / NCOB;
    int co = cob * 16 + (lane & 15);
    int ci = cis * 32 + ((lane >> 4) << 3) + j;
    float val = (co < CO_REAL) ? w[((size_t)co * 64 + ci) * KK + kk] : 0.f;
    wp[idx] = f2b(val);
}

// ---------------------------------------------------------------
// MFMA implicit-GEMM conv, K=15, CI=64, bf16 in / fp32 out.
// Input xt: (B, L, 64) bf16. Out: (B, CO_REAL, L) fp32.
// WG = 4 waves; wave tile = 64co x 32l; WG tile = 64co x 128l.
// A-frag = weights from global frag-linear wp (L2-resident).
// B-frag = input from LDS [142 rows][72 pad]; k-shift = row offset.
// ---------------------------------------------------------------
template<int CO_REAL, int NCOB>
__global__ __launch_bounds__(256) void k_convmfma(
        const unsigned short* __restrict__ xt,
        const unsigned short* __restrict__ wp,
        const float* __restrict__ bias, float* __restrict__ out) {
    __shared__ unsigned short in_lds[142 * 72];
    const int NCOT = NCOB / 4;      // 64-co tiles
    int tid = threadIdx.x;
    int bid = blockIdx.x;
    int lt = bid & 31;
    int cot = (bid >> 5) % NCOT;
    int b = bid / (32 * NCOT);
    int l0 = lt * 128;
    // stage 142 rows x 64 ci (halo rows zero-padded at batch edges)
#pragma unroll
    for (int i = 0; i < 5; ++i) {
        int q = i * 256 + tid;
        if (q < 1136) {
            int r = q >> 3, c8 = (q & 7) * 8;
            int gl = l0 - 7 + r;
            s8v v = {0,0,0,0,0,0,0,0};
            if (gl >= 0 && gl < LL)
                v = *(const s8v*)&xt[((size_t)b * LL + gl) * 64 + c8];
            *(s8v*)&in_lds[r * 72 + c8] = v;
        }
    }
    __syncthreads();
    int lane = tid & 63, wv = tid >> 6;
    int corow = (lane >> 4) << 2;
    f4v acc[4][2];
#pragma unroll
    for (int mt = 0; mt < 4; ++mt) {
#pragma unroll
        for (int r = 0; r < 4; ++r) {
            int co = cot * 64 + mt * 16 + corow + r;
            float bv = (co < CO_REAL) ? bias[co] : 0.f;
            acc[mt][0][r] = bv;
            acc[mt][1][r] = bv;
        }
    }
    int bcol = lane & 15;
    int cig = (lane >> 4) << 3;
    for (int k = 0; k < KK; ++k) {
#pragma unroll
        for (int cis = 0; cis < 2; ++cis) {
            frag_u a[4], bf[2];
#pragma unroll
            for (int mt = 0; mt < 4; ++mt)
                a[mt].s = *(const s8v*)&wp[((((k * NCOB + cot * 4 + mt) * 2 + cis) << 9)
                                           + (lane << 3))];
#pragma unroll
            for (int nt = 0; nt < 2; ++nt)
                bf[nt].s = *(const s8v*)&in_lds[(wv * 32 + nt * 16 + bcol + k) * 72
                                               + cis * 32 + cig];
#pragma unroll
            for (int mt = 0; mt < 4; ++mt)
#pragma unroll
                for (int nt = 0; nt < 2; ++nt)
                    acc[mt][nt] = __builtin_amdgcn_mfma_f32_16x16x32_bf16(
                        a[mt].b, bf[nt].b, acc[mt][nt], 0, 0, 0);
        }
    }
#pragma unroll
    for (int mt = 0; mt < 4; ++mt)
#pragma unroll
        for (int nt = 0; nt < 2; ++nt) {
            int l = l0 + wv * 32 + nt * 16 + bcol;
#pragma unroll
            for (int r = 0; r < 4; ++r) {
                int co = cot * 64 + mt * 16 + corow + r;
                if (co < CO_REAL)
                    out[((size_t)b * CO_REAL + co) * LL + l] = acc[mt][nt][r];
            }
        }
}

// ---------------------------------------------------------------
// in_proj GEMM: C(32768,256) = A^T-view * W(256,64)^T
// ---------------------------------------------------------------
__global__ __launch_bounds__(256) void k_gemm_inproj(const float* __restrict__ A,
        const float* __restrict__ W, float* __restrict__ C) {
    __shared__ float At[64 * 132];
    __shared__ float Wt[64 * 132];
    int tid = threadIdx.x;
    int bid = blockIdx.x;
    int nb = bid & 1;
    int mb = bid >> 1;
    int row0 = mb * 128;
    int n0 = nb * 128;
    int b = row0 >> 12;
    int l0 = row0 & 4095;
#pragma unroll
    for (int it = 0; it < 8; ++it) {
        int idx = it * 256 + tid;
        int k = idx >> 5, m4 = (idx & 31) * 4;
        float4 v = *(const float4*)(A + ((size_t)b * DD + k) * LL + l0 + m4);
        *(float4*)&At[k * 132 + m4] = v;
    }
#pragma unroll
    for (int it = 0; it < 8; ++it) {
        int lin = it * 1024 + tid * 4;
        int n = lin >> 6, k = lin & 63;
        float4 v = *(const float4*)(W + (size_t)(n0 + n) * 64 + k);
        Wt[(k+0)*132 + n] = v.x; Wt[(k+1)*132 + n] = v.y;
        Wt[(k+2)*132 + n] = v.z; Wt[(k+3)*132 + n] = v.w;
    }
    __syncthreads();
    int tx = tid & 15, ty = tid >> 4;
    float acc[2][2][4][4] = {};
#pragma unroll 4
    for (int k = 0; k < 64; ++k) {
        float4 aLo = *(float4*)&At[k*132 + ty*4];
        float4 aHi = *(float4*)&At[k*132 + 64 + ty*4];
        float4 bLo = *(float4*)&Wt[k*132 + tx*4];
        float4 bHi = *(float4*)&Wt[k*132 + 64 + tx*4];
        float a0[4] = {aLo.x, aLo.y, aLo.z, aLo.w};
        float a1[4] = {aHi.x, aHi.y, aHi.z, aHi.w};
        float b0[4] = {bLo.x, bLo.y, bLo.z, bLo.w};
        float b1[4] = {bHi.x, bHi.y, bHi.z, bHi.w};
#pragma unroll
        for (int mm = 0; mm < 4; ++mm)
#pragma unroll
            for (int nn = 0; nn < 4; ++nn) {
                acc[0][0][mm][nn] += a0[mm] * b0[nn];
                acc[0][1][mm][nn] += a0[mm] * b1[nn];
                acc[1][0][mm][nn] += a1[mm] * b0[nn];
                acc[1][1][mm][nn] += a1[mm] * b1[nn];
            }
    }
#pragma unroll
    for (int qm = 0; qm < 2; ++qm)
#pragma unroll
        for (int mm = 0; mm < 4; ++mm) {
            int row = row0 + qm*64 + ty*4 + mm;
#pragma unroll
            for (int qn = 0; qn < 2; ++qn) {
                float4 v = make_float4(acc[qm][qn][mm][0], acc[qm][qn][mm][1],
                                       acc[qm][qn][mm][2], acc[qm][qn][mm][3]);
                *(float4*)(C + (size_t)row * 256 + n0 + qn*64 + tx*4) = v;
            }
        }
}

// ---------------------------------------------------------------
// x_proj GEMM: dbl(32768,64) = A(32768,128) * W(36,128)^T (zero-padded)
// ---------------------------------------------------------------
template<int NW, bool GUARD>
__global__ __launch_bounds__(256) void k_gemm64(const float* __restrict__ A,
        const float* __restrict__ W, float* __restrict__ out) {
    __shared__ float At[64 * 132];
    __shared__ float Wt[64 * 68];
    int tid = threadIdx.x;
    int row0 = blockIdx.x * 128;
    int tx = tid & 15, ty = tid >> 4;
    float acc[2][4][4] = {};
#pragma unroll
    for (int kt = 0; kt < 2; ++kt) {
        __syncthreads();
#pragma unroll
        for (int it = 0; it < 8; ++it) {
            int lin = it * 1024 + tid * 4;
            int m = lin >> 6, k = lin & 63;
            float4 v = *(const float4*)(A + (size_t)(row0 + m) * 128 + kt*64 + k);
            At[(k+0)*132 + m] = v.x; At[(k+1)*132 + m] = v.y;
            At[(k+2)*132 + m] = v.z; At[(k+3)*132 + m] = v.w;
        }
#pragma unroll
        for (int it = 0; it < 4; ++it) {
            int lin = it * 1024 + tid * 4;
            int n = lin >> 6, k = lin & 63;
            float4 v = make_float4(0.f, 0.f, 0.f, 0.f);
            if (!GUARD || n < NW)
                v = *(const float4*)(W + (size_t)n * 128 + kt*64 + k);
            Wt[(k+0)*68 + n] = v.x; Wt[(k+1)*68 + n] = v.y;
            Wt[(k+2)*68 + n] = v.z; Wt[(k+3)*68 + n] = v.w;
        }
        __syncthreads();
#pragma unroll 4
        for (int k = 0; k < 64; ++k) {
            float4 aLo = *(float4*)&At[k*132 + ty*4];
            float4 aHi = *(float4*)&At[k*132 + 64 + ty*4];
            float4 b4  = *(float4*)&Wt[k*68 + tx*4];
            float a0[4] = {aLo.x, aLo.y, aLo.z, aLo.w};
            float a1[4] = {aHi.x, aHi.y, aHi.z, aHi.w};
            float bv[4] = {b4.x, b4.y, b4.z, b4.w};
#pragma unroll
            for (int mm = 0; mm < 4; ++mm)
#pragma unroll
                for (int nn = 0; nn < 4; ++nn) {
                    acc[0][mm][nn] += a0[mm] * bv[nn];
                    acc[1][mm][nn] += a1[mm] * bv[nn];
                }
        }
    }
#pragma unroll
    for (int qm = 0; qm < 2; ++qm)
#pragma unroll
        for (int mm = 0; mm < 4; ++mm) {
            int row = row0 + qm*64 + ty*4 + mm;
            *(float4*)(out + (size_t)row * 64 + tx*4) =
                make_float4(acc[qm][mm][0], acc[qm][mm][1],
                            acc[qm][mm][2], acc[qm][mm][3]);
        }
}

// ---------------------------------------------------------------
// out_proj GEMM + residual + bf16 transposed write to (B,L,64).
// ---------------------------------------------------------------
__global__ __launch_bounds__(256) void k_gemm64_tr(const float* __restrict__ A,
        const float* __restrict__ W, const float* __restrict__ res,
        unsigned short* __restrict__ out) {
    __shared__ float smem[13312];
    float* At = smem;
    float* Wt = smem + 64*132;
    int tid = threadIdx.x;
    int row0 = blockIdx.x * 128;
    int tx = tid & 15, ty = tid >> 4;
    int b = row0 >> 12, l0 = row0 & 4095;
    float acc[2][4][4] = {};
#pragma unroll
    for (int kt = 0; kt < 2; ++kt) {
        __syncthreads();
#pragma unroll
        for (int it = 0; it < 8; ++it) {
            int lin = it * 1024 + tid * 4;
            int m = lin >> 6, k = lin & 63;
            float4 v = *(const float4*)(A + (size_t)(row0 + m) * 128 + kt*64 + k);
            At[(k+0)*132 + m] = v.x; At[(k+1)*132 + m] = v.y;
            At[(k+2)*132 + m] = v.z; At[(k+3)*132 + m] = v.w;
        }
#pragma unroll
        for (int it = 0; it < 4; ++it) {
            int lin = it * 1024 + tid * 4;
            int n = lin >> 6, k = lin & 63;
            float4 v = *(const float4*)(W + (size_t)n * 128 + kt*64 + k);
            Wt[(k+0)*68 + n] = v.x; Wt[(k+1)*68 + n] = v.y;
            Wt[(k+2)*68 + n] = v.z; Wt[(k+3)*68 + n] = v.w;
        }
        __syncthreads();
#pragma unroll 4
        for (int k = 0; k < 64; ++k) {
            float4 aLo = *(float4*)&At[k*132 + ty*4];
            float4 aHi = *(float4*)&At[k*132 + 64 + ty*4];
            float4 b4  = *(float4*)&Wt[k*68 + tx*4];
            float a0[4] = {aLo.x, aLo.y, aLo.z, aLo.w};
            float a1[4] = {aHi.x, aHi.y, aHi.z, aHi.w};
            float bv[4] = {b4.x, b4.y, b4.z, b4.w};
#pragma unroll
            for (int mm = 0; mm < 4; ++mm)
#pragma unroll
                for (int nn = 0; nn < 4; ++nn) {
                    acc[0][mm][nn] += a0[mm] * bv[nn];
                    acc[1][mm][nn] += a1[mm] * bv[nn];
                }
        }
    }
    __syncthreads();
    float* tile = smem;                               // [128][68] fp32
    unsigned short* resb = (unsigned short*)(smem + 8704);  // [128][72] bf16
#pragma unroll
    for (int qm = 0; qm < 2; ++qm)
#pragma unroll
        for (int mm = 0; mm < 4; ++mm) {
            int lrow = qm*64 + ty*4 + mm;
            *(float4*)&tile[lrow*68 + tx*4] = make_float4(
                acc[qm][mm][0], acc[qm][mm][1], acc[qm][mm][2], acc[qm][mm][3]);
        }
    // stage residual (B,64,L) -> resb[l][d] bf16, coalesced reads
#pragma unroll
    for (int it = 0; it < 8; ++it) {
        int idx = it * 256 + tid;
        int d = idx >> 5, l4 = (idx & 31) * 4;
        float4 rv = *(const float4*)(res + ((size_t)b * DD + d) * LL + l0 + l4);
        resb[(l4+0)*72 + d] = f2b(rv.x);
        resb[(l4+1)*72 + d] = f2b(rv.y);
        resb[(l4+2)*72 + d] = f2b(rv.z);
        resb[(l4+3)*72 + d] = f2b(rv.w);
    }
    __syncthreads();
#pragma unroll
    for (int it = 0; it < 4; ++it) {
        int idx = it * 256 + tid;
        int l = idx >> 3, c8 = (idx & 7) * 8;
        unsigned short o[8];
#pragma unroll
        for (int j = 0; j < 8; ++j)
            o[j] = f2b(tile[l*68 + c8 + j] + b2f(resb[l*72 + c8 + j]));
        *(s8v*)&out[((size_t)b * LL + l0 + l) * 64 + c8] = *(s8v*)o;
    }
}

// ---------------------------------------------------------------
// Depthwise causal conv (DC=4) + silu.
// ---------------------------------------------------------------
__global__ __launch_bounds__(256) void k_dwconv(const float* __restrict__ xz,
        const float* __restrict__ w, const float* __restrict__ bias,
        float* __restrict__ xs_act) {
    int idx = blockIdx.x * 256 + threadIdx.x;   // B*L*128
    int d = idx & 127;
    int row = idx >> 7;
    int l = row & (LL - 1);
    float s = bias[d];
    const float* wp = w + d * 4;
#pragma unroll
    for (int j = 0; j < 4; ++j) {
        int li = l - 3 + j;
        if (li >= 0) s += xz[(size_t)(row - 3 + j) * 256 + d] * wp[j];
    }
    float sg = 1.f / (1.f + __expf(-s));
    xs_act[idx] = s * sg;
}

// ---------------------------------------------------------------
// dt = softplus(dbl[:, :4] @ dt_proj_w^T + b)
// ---------------------------------------------------------------
__global__ __launch_bounds__(256) void k_dtproj(const float* __restrict__ dbl,
        const float* __restrict__ w, const float* __restrict__ bias,
        float* __restrict__ dt) {
    int idx = blockIdx.x * 256 + threadIdx.x;   // B*L*128
    int d = idx & 127;
    int row = idx >> 7;
    float4 di = *(const float4*)(dbl + (size_t)row * 64);
    float4 w4 = *(const float4*)(w + d * 4);
    float v = di.x*w4.x + di.y*w4.y + di.z*w4.z + di.w*w4.w + bias[d];
    dt[idx] = (v > 15.f) ? v : log1pf(__expf(v));
}

// ---------------------------------------------------------------
// Scan phase 1.
// ---------------------------------------------------------------
__global__ __launch_bounds__(256) void k_scan1(const float* __restrict__ dt,
        const float* __restrict__ xs, const float* __restrict__ dbl,
        const float* __restrict__ A_log, float* __restrict__ P,
        float* __restrict__ Q) {
    int tid = threadIdx.x, lane = tid & 63;
    int s = lane & 15, dloc = lane >> 4;
    int wg = blockIdx.x * 4 + (tid >> 6);
    int c = wg & 31, dg = (wg >> 5) & 31, b = wg >> 10;
    int d = dg * 4 + dloc;
    float Ads = -__expf(A_log[d * DSx + s]);
    size_t base = (size_t)b * LL + (size_t)c * CLEN;
    const float* pdt = dt + base * 128 + d;
    const float* pxs = xs + base * 128 + d;
    const float* pB  = dbl + base * 64 + 4 + s;
    float h = 0.f, p = 1.f;
    for (int t = 0; t < CLEN; t += 8) {
#pragma unroll
        for (int u = 0; u < 8; ++u) {
            float dtv = pdt[u * 128];
            float xv  = pxs[u * 128];
            float Bv  = pB[u * 64];
            float da  = __expf(dtv * Ads);
            h = da * h + dtv * xv * Bv;
            p *= da;
        }
        pdt += 1024; pxs += 1024; pB += 512;
    }
    int chain = (b * DIx + d) * DSx + s;
    P[(size_t)c * 16384 + chain] = p;
    Q[(size_t)c * 16384 + chain] = h;
}

// ---------------------------------------------------------------
// Scan phase 2 (+ zero BN stats accum).
// ---------------------------------------------------------------
__global__ __launch_bounds__(256) void k_scan2(const float* __restrict__ P,
        const float* __restrict__ Q, float* __restrict__ Hin,
        float* __restrict__ stats) {
    int chain = blockIdx.x * 256 + threadIdx.x;  // 16384
    if (blockIdx.x == 0 && threadIdx.x < 128) stats[threadIdx.x] = 0.f;
    float carry = 0.f;
    for (int c = 0; c < NCH; ++c) {
        Hin[(size_t)c * 16384 + chain] = carry;
        carry = P[(size_t)c * 16384 + chain] * carry + Q[(size_t)c * 16384 + chain];
    }
}

// ---------------------------------------------------------------
// Scan phase 3.
// ---------------------------------------------------------------
__global__ __launch_bounds__(256) void k_scan3(const float* __restrict__ dt,
        const float* __restrict__ xs, const float* __restrict__ dbl,
        const float* __restrict__ A_log, const float* __restrict__ Hin,
        const float* __restrict__ xz, const float* __restrict__ Dssm,
        float* __restrict__ ym) {
    int tid = threadIdx.x, lane = tid & 63;
    int s = lane & 15, dloc = lane >> 4;
    int wg = blockIdx.x * 4 + (tid >> 6);
    int c = wg & 31, dg = (wg >> 5) & 31, b = wg >> 10;
    int d = dg * 4 + dloc;
    float Ads = -__expf(A_log[d * DSx + s]);
    int chain = (b * DIx + d) * DSx + s;
    float h = Hin[(size_t)c * 16384 + chain];
    float Dv = Dssm[d];
    size_t base = (size_t)b * LL + (size_t)c * CLEN;
    const float* pdt = dt + base * 128 + d;
    const float* pxs = xs + base * 128 + d;
    const float* pB  = dbl + base * 64 + 4 + s;
    const float* pC  = dbl + base * 64 + 20 + s;
    const float* pz  = xz + base * 256 + 128 + d;
    float* pym = ym + base * 128 + d;
    for (int t = 0; t < CLEN; t += 8) {
#pragma unroll
        for (int u = 0; u < 8; ++u) {
            float dtv = pdt[u * 128];
            float xv  = pxs[u * 128];
            float Bv  = pB[u * 64];
            float Cv  = pC[u * 64];
            float da  = __expf(dtv * Ads);
            h = da * h + dtv * xv * Bv;
            float part = h * Cv;
            part += __shfl_xor(part, 1);
            part += __shfl_xor(part, 2);
            part += __shfl_xor(part, 4);
            part += __shfl_xor(part, 8);
            if (s == 0) {
                float y = part + xv * Dv;
                float zv = pz[u * 256];
                y *= zv / (1.f + __expf(-zv));
                pym[u * 128] = y;
            }
        }
        pdt += 1024; pxs += 1024; pB += 512; pC += 512; pz += 2048; pym += 1024;
    }
}

// ---------------------------------------------------------------
// BN partial sums.
// ---------------------------------------------------------------
__global__ __launch_bounds__(256) void k_bnpart(const float* __restrict__ xm,
        float* __restrict__ stats) {
    int c = blockIdx.x >> 3, b = blockIdx.x & 7;
    const float* p = xm + ((size_t)b * DD + c) * LL;
    int tid = threadIdx.x;
    float s = 0.f, ss = 0.f;
#pragma unroll
    for (int it = 0; it < 4; ++it) {
        float4 v = *(const float4*)(p + (size_t)(it * 256 + tid) * 4);
        s  += v.x + v.y + v.z + v.w;
        ss += v.x*v.x + v.y*v.y + v.z*v.z + v.w*v.w;
    }
    for (int o = 32; o > 0; o >>= 1) {
        s  += __shfl_down(s, o);
        ss += __shfl_down(ss, o);
    }
    __shared__ float red[8];
    int wid = tid >> 6;
    if ((tid & 63) == 0) { red[wid] = s; red[4 + wid] = ss; }
    __syncthreads();
    if (tid == 0) {
        atomicAdd(&stats[c], red[0] + red[1] + red[2] + red[3]);
        atomicAdd(&stats[64 + c], red[4] + red[5] + red[6] + red[7]);
    }
}

// ---------------------------------------------------------------
// BN apply + residual + transpose -> bf16 (B,L,64) for ps conv.
// Block: 64l x 64c tile.
// ---------------------------------------------------------------
__global__ __launch_bounds__(256) void k_bnapply_t(const float* __restrict__ xm,
        const float* __restrict__ stats, const float* __restrict__ gamma,
        const float* __restrict__ beta, const float* __restrict__ xin,
        unsigned short* __restrict__ xf) {
    __shared__ float t[64][65];
    int tid = threadIdx.x;
    int b = blockIdx.x >> 6;
    int l0 = (blockIdx.x & 63) * 64;
    const float inv = 1.f / (float)(BB * LL);
#pragma unroll
    for (int it = 0; it < 16; ++it) {
        int idx = it * 256 + tid;
        int c = idx >> 6, l = idx & 63;
        float mean = stats[c] * inv;
        float var  = stats[64 + c] * inv - mean * mean;
        float g = gamma[c] * rsqrtf(var + 1e-5f);
        float sh = beta[c] - mean * g;
        size_t addr = ((size_t)b * DD + c) * LL + l0 + l;
        t[c][l] = xm[addr] * g + sh + xin[addr];
    }
    __syncthreads();
#pragma unroll
    for (int it = 0; it < 2; ++it) {
        int idx = it * 256 + tid;
        int l = idx >> 3, c8 = (idx & 7) * 8;
        unsigned short o[8];
#pragma unroll
        for (int j = 0; j < 8; ++j) o[j] = f2b(t[c8 + j][l]);
        *(s8v*)&xf[((size_t)b * LL + l0 + l) * 64 + c8] = *(s8v*)o;
    }
}

// ---------------------------------------------------------------
// PixelShuffle(r=10) + linear upsample of x + add -> d_out
// ---------------------------------------------------------------
__global__ __launch_bounds__(256) void k_final(const float* __restrict__ xp,
        const float* __restrict__ x, float* __restrict__ out) {
    int i = blockIdx.x * 256 + threadIdx.x;     // B*12*OUTL
    int j = i % OUTL;
    int c = (i / OUTL) % 12;
    int b = i / (OUTL * 12);
    int r = j % RR, l = j / RR;
    float ps = xp[((size_t)b * 120 + r * 12 + c) * LL + l];
    float src = ((float)j + 0.5f) * 0.1f - 0.5f;
    src = fmaxf(src, 0.f);
    int i0 = (int)src;
    if (i0 > LL - 1) i0 = LL - 1;
    int i1 = (i0 + 1 < LL) ? i0 + 1 : LL - 1;
    float frac = src - (float)i0;
    const float* xr = x + ((size_t)b * 12 + c) * LL;
    float up = xr[i0] * (1.f - frac) + xr[i1] * frac;
    out[i] = ps + up;
}

// ---------------------------------------------------------------
extern "C" void kernel_launch(void* const* d_in, const int* in_sizes, int n_in,
                              void* d_out, int out_size, void* d_ws, size_t ws_size,
                              hipStream_t stream) {
    const float* x          = (const float*)d_in[0];
    const float* conv_in_w  = (const float*)d_in[1];
    const float* conv_in_b  = (const float*)d_in[2];
    const float* in_proj_w  = (const float*)d_in[3];
    const float* dw_w       = (const float*)d_in[4];
    const float* dw_b       = (const float*)d_in[5];
    const float* x_proj_w   = (const float*)d_in[6];
    const float* dt_w       = (const float*)d_in[7];
    const float* dt_b       = (const float*)d_in[8];
    const float* A_log      = (const float*)d_in[9];
    const float* Dssm       = (const float*)d_in[10];
    const float* out_proj_w = (const float*)d_in[11];
    const float* cm_w       = (const float*)d_in[12];
    const float* cm_b       = (const float*)d_in[13];
    const float* bn_g       = (const float*)d_in[14];
    const float* bn_be      = (const float*)d_in[15];
    const float* ps_w       = (const float*)d_in[16];
    const float* ps_b       = (const float*)d_in[17];

    float* ws = (float*)d_ws;
    float* xin_bdl = ws;                       //  2,097,152
    float* xz      = ws + 2097152;             //  8,388,608
    float* xs_act  = ws + 10485760;            //  4,194,304
    float* dbl64   = ws + 14680064;            //  2,097,152
    float* P       = ws + 16777216;            //    524,288
    float* Q       = ws + 17301504;            //    524,288
    float* Hin     = ws + 17825792;            //    524,288
    float* ym      = ws + 18350080;            //  4,194,304
    unsigned short* xmt = (unsigned short*)(ws + 22544384);  // 2.09M bf16
    unsigned short* xf  = (unsigned short*)(ws + 23592960);  // 2.09M bf16
    float* xmerge  = ws + 24641536;            //  2,097,152
    float* stats   = ws + 26738688;            //        128
    float* dtb     = ws + 26738816;            //  4,194,304
    // xz tail reuse (free after scan3; xp only uses first 3.93M of xz):
    unsigned short* wp_ps = (unsigned short*)(ws + 6029312);  // 122,880 bf16
    unsigned short* wp_mg = (unsigned short*)(ws + 6090752);  //  61,440 bf16
    float* xp      = xz;

    k_conv<CIN, 64, 2, true><<<1024, 256, 0, stream>>>(x, conv_in_w, conv_in_b, xin_bdl);
    k_gemm_inproj<<<512, 256, 0, stream>>>(xin_bdl, in_proj_w, xz);
    k_dwconv<<<16384, 256, 0, stream>>>(xz, dw_w, dw_b, xs_act);
    k_gemm64<36, true><<<256, 256, 0, stream>>>(xs_act, x_proj_w, dbl64);
    k_dtproj<<<16384, 256, 0, stream>>>(dbl64, dt_w, dt_b, dtb);
    k_scan1<<<2048, 256, 0, stream>>>(dtb, xs_act, dbl64, A_log, P, Q);
    k_scan2<<<64, 256, 0, stream>>>(P, Q, Hin, stats);
    k_scan3<<<2048, 256, 0, stream>>>(dtb, xs_act, dbl64, A_log, Hin, xz, Dssm, ym);
    // weight prep (after scan3: wp buffers live in xz tail)
    k_wprep<120, 8><<<480, 256, 0, stream>>>(ps_w, wp_ps);
    k_wprep<64, 4><<<240, 256, 0, stream>>>(cm_w, wp_mg);
    k_gemm64_tr<<<256, 256, 0, stream>>>(ym, out_proj_w, xin_bdl, xmt);
    k_convmfma<64, 4><<<256, 256, 0, stream>>>(xmt, wp_mg, cm_b, xmerge);
    k_bnpart<<<512, 256, 0, stream>>>(xmerge, stats);
    k_bnapply_t<<<512, 256, 0, stream>>>(xmerge, stats, bn_g, bn_be, xin_bdl, xf);
    k_convmfma<120, 8><<<512, 256, 0, stream>>>(xf, wp_ps, ps_b, xp);
    k_final<<<15360, 256, 0, stream>>>(xp, x, (float*)d_out);
}

// Round 7
// 343.848 us; speedup vs baseline: 1.7527x; 1.1649x over previous
//
#include <hip/hip_runtime.h>
#include <math.h>

#define BB 8
#define CIN 12
#define LL 4096
#define DD 64
#define DIx 128
#define DSx 16
#define RR 10
#define KK 15
#define NCH 256     // scan chunks
#define CLEN 16     // LL/NCH
#define OUTL 40960  // LL*RR

typedef __attribute__((ext_vector_type(8))) short s8v;
typedef __attribute__((ext_vector_type(8))) __bf16 b8v;
typedef __attribute__((ext_vector_type(4))) float f4v;
union frag_u { s8v s; b8v b; };

__device__ __forceinline__ unsigned short f2b(float f) {
    unsigned int u = __float_as_uint(f);
    u = (u + 0x7fffu + ((u >> 16) & 1u)) >> 16;
    return (unsigned short)u;
}
__device__ __forceinline__ float b2f(unsigned short h) {
    return __uint_as_float(((unsigned int)h) << 16);
}

// ---------------------------------------------------------------
// Direct conv1d fp32 (kept for conv_in, CI=12 only).
// ---------------------------------------------------------------
template<int CI, int CO, int COT, bool LEAKY>
__global__ __launch_bounds__(256) void k_conv(const float* __restrict__ in,
        const float* __restrict__ w, const float* __restrict__ bias,
        float* __restrict__ out) {
    const int LT = 1024;
    int tid = threadIdx.x;
    int bid = blockIdx.x;
    const int nlt = LL / LT;        // 4
    const int ncog = CO / COT;
    int lt = bid % nlt;
    int cog = (bid / nlt) % ncog;
    int b = bid / (nlt * ncog);
    int l0 = lt * LT + tid * 4;
    int co0 = cog * COT;

    float acc[COT][4];
#pragma unroll
    for (int c = 0; c < COT; ++c) {
        float bv = bias[co0 + c];
#pragma unroll
        for (int j = 0; j < 4; ++j) acc[c][j] = bv;
    }
    for (int ci = 0; ci < CI; ++ci) {
        const float* inp = in + ((size_t)b * CI + ci) * LL;
        float in20[20];
#pragma unroll
        for (int q = 0; q < 5; ++q) {
            int gi = l0 - 8 + q * 4;
            if (gi >= 0 && gi + 3 < LL) {
                float4 v = *(const float4*)(inp + gi);
                in20[q*4+0] = v.x; in20[q*4+1] = v.y;
                in20[q*4+2] = v.z; in20[q*4+3] = v.w;
            } else {
#pragma unroll
                for (int j = 0; j < 4; ++j) {
                    int g = gi + j;
                    in20[q*4+j] = (g >= 0 && g < LL) ? inp[g] : 0.f;
                }
            }
        }
#pragma unroll
        for (int c = 0; c < COT; ++c) {
            const float* wp = w + ((size_t)(co0 + c) * CI + ci) * KK;
#pragma unroll
            for (int k = 0; k < KK; ++k) {
                float wv = wp[k];
#pragma unroll
                for (int j = 0; j < 4; ++j)
                    acc[c][j] += wv * in20[j + k + 1];
            }
        }
    }
#pragma unroll
    for (int c = 0; c < COT; ++c) {
        float r[4];
#pragma unroll
        for (int j = 0; j < 4; ++j) {
            float v = acc[c][j];
            if (LEAKY) v = (v >= 0.f) ? v : 0.01f * v;
            r[j] = v;
        }
        *(float4*)(out + ((size_t)b * CO + co0 + c) * LL + l0) =
            make_float4(r[0], r[1], r[2], r[3]);
    }
}

// ---------------------------------------------------------------
// Weight prep: frag-linear bf16 for MFMA A-operand.
// ---------------------------------------------------------------
template<int CO_REAL, int NCOB>
__global__ __launch_bounds__(256) void k_wprep(const float* __restrict__ w,
        unsigned short* __restrict__ wp) {
    int idx = blockIdx.x * 256 + threadIdx.x;
    if (idx >= 15 * NCOB * 1024) return;
    int j = idx & 7;
    int lane = (idx >> 3) & 63;
    int cis = (idx >> 9) & 1;
    int rest = idx >> 10;
    int cob = rest % NCOB;
    int kk = rest / NCOB;
    int co = cob * 16 + (lane & 15);
    int ci = cis * 32 + ((lane >> 4) << 3) + j;
    float val = (co < CO_REAL) ? w[((size_t)co * 64 + ci) * KK + kk] : 0.f;
    wp[idx] = f2b(val);
}

// ---------------------------------------------------------------
// MFMA implicit-GEMM conv, K=15, CI=64, bf16 in / fp32 out.
// ---------------------------------------------------------------
template<int CO_REAL, int NCOB>
__global__ __launch_bounds__(256) void k_convmfma(
        const unsigned short* __restrict__ xt,
        const unsigned short* __restrict__ wp,
        const float* __restrict__ bias, float* __restrict__ out) {
    __shared__ unsigned short in_lds[142 * 72];
    const int NCOT = NCOB / 4;      // 64-co tiles
    int tid = threadIdx.x;
    int bid = blockIdx.x;
    int lt = bid & 31;
    int cot = (bid >> 5) % NCOT;
    int b = bid / (32 * NCOT);
    int l0 = lt * 128;
#pragma unroll
    for (int i = 0; i < 5; ++i) {
        int q = i * 256 + tid;
        if (q < 1136) {
            int r = q >> 3, c8 = (q & 7) * 8;
            int gl = l0 - 7 + r;
            s8v v = {0,0,0,0,0,0,0,0};
            if (gl >= 0 && gl < LL)
                v = *(const s8v*)&xt[((size_t)b * LL + gl) * 64 + c8];
            *(s8v*)&in_lds[r * 72 + c8] = v;
        }
    }
    __syncthreads();
    int lane = tid & 63, wv = tid >> 6;
    int corow = (lane >> 4) << 2;
    f4v acc[4][2];
#pragma unroll
    for (int mt = 0; mt < 4; ++mt) {
#pragma unroll
        for (int r = 0; r < 4; ++r) {
            int co = cot * 64 + mt * 16 + corow + r;
            float bv = (co < CO_REAL) ? bias[co] : 0.f;
            acc[mt][0][r] = bv;
            acc[mt][1][r] = bv;
        }
    }
    int bcol = lane & 15;
    int cig = (lane >> 4) << 3;
    for (int k = 0; k < KK; ++k) {
#pragma unroll
        for (int cis = 0; cis < 2; ++cis) {
            frag_u a[4], bf[2];
#pragma unroll
            for (int mt = 0; mt < 4; ++mt)
                a[mt].s = *(const s8v*)&wp[((((k * NCOB + cot * 4 + mt) * 2 + cis) << 9)
                                           + (lane << 3))];
#pragma unroll
            for (int nt = 0; nt < 2; ++nt)
                bf[nt].s = *(const s8v*)&in_lds[(wv * 32 + nt * 16 + bcol + k) * 72
                                               + cis * 32 + cig];
#pragma unroll
            for (int mt = 0; mt < 4; ++mt)
#pragma unroll
                for (int nt = 0; nt < 2; ++nt)
                    acc[mt][nt] = __builtin_amdgcn_mfma_f32_16x16x32_bf16(
                        a[mt].b, bf[nt].b, acc[mt][nt], 0, 0, 0);
        }
    }
#pragma unroll
    for (int mt = 0; mt < 4; ++mt)
#pragma unroll
        for (int nt = 0; nt < 2; ++nt) {
            int l = l0 + wv * 32 + nt * 16 + bcol;
#pragma unroll
            for (int r = 0; r < 4; ++r) {
                int co = cot * 64 + mt * 16 + corow + r;
                if (co < CO_REAL)
                    out[((size_t)b * CO_REAL + co) * LL + l] = acc[mt][nt][r];
            }
        }
}

// ---------------------------------------------------------------
// in_proj GEMM: C(32768,256) = A^T-view * W(256,64)^T
// ---------------------------------------------------------------
__global__ __launch_bounds__(256) void k_gemm_inproj(const float* __restrict__ A,
        const float* __restrict__ W, float* __restrict__ C) {
    __shared__ float At[64 * 132];
    __shared__ float Wt[64 * 132];
    int tid = threadIdx.x;
    int bid = blockIdx.x;
    int nb = bid & 1;
    int mb = bid >> 1;
    int row0 = mb * 128;
    int n0 = nb * 128;
    int b = row0 >> 12;
    int l0 = row0 & 4095;
#pragma unroll
    for (int it = 0; it < 8; ++it) {
        int idx = it * 256 + tid;
        int k = idx >> 5, m4 = (idx & 31) * 4;
        float4 v = *(const float4*)(A + ((size_t)b * DD + k) * LL + l0 + m4);
        *(float4*)&At[k * 132 + m4] = v;
    }
#pragma unroll
    for (int it = 0; it < 8; ++it) {
        int lin = it * 1024 + tid * 4;
        int n = lin >> 6, k = lin & 63;
        float4 v = *(const float4*)(W + (size_t)(n0 + n) * 64 + k);
        Wt[(k+0)*132 + n] = v.x; Wt[(k+1)*132 + n] = v.y;
        Wt[(k+2)*132 + n] = v.z; Wt[(k+3)*132 + n] = v.w;
    }
    __syncthreads();
    int tx = tid & 15, ty = tid >> 4;
    float acc[2][2][4][4] = {};
#pragma unroll 4
    for (int k = 0; k < 64; ++k) {
        float4 aLo = *(float4*)&At[k*132 + ty*4];
        float4 aHi = *(float4*)&At[k*132 + 64 + ty*4];
        float4 bLo = *(float4*)&Wt[k*132 + tx*4];
        float4 bHi = *(float4*)&Wt[k*132 + 64 + tx*4];
        float a0[4] = {aLo.x, aLo.y, aLo.z, aLo.w};
        float a1[4] = {aHi.x, aHi.y, aHi.z, aHi.w};
        float b0[4] = {bLo.x, bLo.y, bLo.z, bLo.w};
        float b1[4] = {bHi.x, bHi.y, bHi.z, bHi.w};
#pragma unroll
        for (int mm = 0; mm < 4; ++mm)
#pragma unroll
            for (int nn = 0; nn < 4; ++nn) {
                acc[0][0][mm][nn] += a0[mm] * b0[nn];
                acc[0][1][mm][nn] += a0[mm] * b1[nn];
                acc[1][0][mm][nn] += a1[mm] * b0[nn];
                acc[1][1][mm][nn] += a1[mm] * b1[nn];
            }
    }
#pragma unroll
    for (int qm = 0; qm < 2; ++qm)
#pragma unroll
        for (int mm = 0; mm < 4; ++mm) {
            int row = row0 + qm*64 + ty*4 + mm;
#pragma unroll
            for (int qn = 0; qn < 2; ++qn) {
                float4 v = make_float4(acc[qm][qn][mm][0], acc[qm][qn][mm][1],
                                       acc[qm][qn][mm][2], acc[qm][qn][mm][3]);
                *(float4*)(C + (size_t)row * 256 + n0 + qn*64 + tx*4) = v;
            }
        }
}

// ---------------------------------------------------------------
// x_proj GEMM: dbl(32768,64) = A(32768,128) * W(36,128)^T (zero-padded)
// ---------------------------------------------------------------
template<int NW, bool GUARD>
__global__ __launch_bounds__(256) void k_gemm64(const float* __restrict__ A,
        const float* __restrict__ W, float* __restrict__ out) {
    __shared__ float At[64 * 132];
    __shared__ float Wt[64 * 68];
    int tid = threadIdx.x;
    int row0 = blockIdx.x * 128;
    int tx = tid & 15, ty = tid >> 4;
    float acc[2][4][4] = {};
#pragma unroll
    for (int kt = 0; kt < 2; ++kt) {
        __syncthreads();
#pragma unroll
        for (int it = 0; it < 8; ++it) {
            int lin = it * 1024 + tid * 4;
            int m = lin >> 6, k = lin & 63;
            float4 v = *(const float4*)(A + (size_t)(row0 + m) * 128 + kt*64 + k);
            At[(k+0)*132 + m] = v.x; At[(k+1)*132 + m] = v.y;
            At[(k+2)*132 + m] = v.z; At[(k+3)*132 + m] = v.w;
        }
#pragma unroll
        for (int it = 0; it < 4; ++it) {
            int lin = it * 1024 + tid * 4;
            int n = lin >> 6, k = lin & 63;
            float4 v = make_float4(0.f, 0.f, 0.f, 0.f);
            if (!GUARD || n < NW)
                v = *(const float4*)(W + (size_t)n * 128 + kt*64 + k);
            Wt[(k+0)*68 + n] = v.x; Wt[(k+1)*68 + n] = v.y;
            Wt[(k+2)*68 + n] = v.z; Wt[(k+3)*68 + n] = v.w;
        }
        __syncthreads();
#pragma unroll 4
        for (int k = 0; k < 64; ++k) {
            float4 aLo = *(float4*)&At[k*132 + ty*4];
            float4 aHi = *(float4*)&At[k*132 + 64 + ty*4];
            float4 b4  = *(float4*)&Wt[k*68 + tx*4];
            float a0[4] = {aLo.x, aLo.y, aLo.z, aLo.w};
            float a1[4] = {aHi.x, aHi.y, aHi.z, aHi.w};
            float bv[4] = {b4.x, b4.y, b4.z, b4.w};
#pragma unroll
            for (int mm = 0; mm < 4; ++mm)
#pragma unroll
                for (int nn = 0; nn < 4; ++nn) {
                    acc[0][mm][nn] += a0[mm] * bv[nn];
                    acc[1][mm][nn] += a1[mm] * bv[nn];
                }
        }
    }
#pragma unroll
    for (int qm = 0; qm < 2; ++qm)
#pragma unroll
        for (int mm = 0; mm < 4; ++mm) {
            int row = row0 + qm*64 + ty*4 + mm;
            *(float4*)(out + (size_t)row * 64 + tx*4) =
                make_float4(acc[qm][mm][0], acc[qm][mm][1],
                            acc[qm][mm][2], acc[qm][mm][3]);
        }
}

// ---------------------------------------------------------------
// out_proj GEMM + residual + bf16 transposed write to (B,L,64).
// ---------------------------------------------------------------
__global__ __launch_bounds__(256) void k_gemm64_tr(const float* __restrict__ A,
        const float* __restrict__ W, const float* __restrict__ res,
        unsigned short* __restrict__ out) {
    __shared__ float smem[13312];
    float* At = smem;
    float* Wt = smem + 64*132;
    int tid = threadIdx.x;
    int row0 = blockIdx.x * 128;
    int tx = tid & 15, ty = tid >> 4;
    int b = row0 >> 12, l0 = row0 & 4095;
    float acc[2][4][4] = {};
#pragma unroll
    for (int kt = 0; kt < 2; ++kt) {
        __syncthreads();
#pragma unroll
        for (int it = 0; it < 8; ++it) {
            int lin = it * 1024 + tid * 4;
            int m = lin >> 6, k = lin & 63;
            float4 v = *(const float4*)(A + (size_t)(row0 + m) * 128 + kt*64 + k);
            At[(k+0)*132 + m] = v.x; At[(k+1)*132 + m] = v.y;
            At[(k+2)*132 + m] = v.z; At[(k+3)*132 + m] = v.w;
        }
#pragma unroll
        for (int it = 0; it < 4; ++it) {
            int lin = it * 1024 + tid * 4;
            int n = lin >> 6, k = lin & 63;
            float4 v = *(const float4*)(W + (size_t)n * 128 + kt*64 + k);
            Wt[(k+0)*68 + n] = v.x; Wt[(k+1)*68 + n] = v.y;
            Wt[(k+2)*68 + n] = v.z; Wt[(k+3)*68 + n] = v.w;
        }
        __syncthreads();
#pragma unroll 4
        for (int k = 0; k < 64; ++k) {
            float4 aLo = *(float4*)&At[k*132 + ty*4];
            float4 aHi = *(float4*)&At[k*132 + 64 + ty*4];
            float4 b4  = *(float4*)&Wt[k*68 + tx*4];
            float a0[4] = {aLo.x, aLo.y, aLo.z, aLo.w};
            float a1[4] = {aHi.x, aHi.y, aHi.z, aHi.w};
            float bv[4] = {b4.x, b4.y, b4.z, b4.w};
#pragma unroll
            for (int mm = 0; mm < 4; ++mm)
#pragma unroll
                for (int nn = 0; nn < 4; ++nn) {
                    acc[0][mm][nn] += a0[mm] * bv[nn];
                    acc[1][mm][nn] += a1[mm] * bv[nn];
                }
        }
    }
    __syncthreads();
    float* tile = smem;                               // [128][68] fp32
    unsigned short* resb = (unsigned short*)(smem + 8704);  // [128][72] bf16
#pragma unroll
    for (int qm = 0; qm < 2; ++qm)
#pragma unroll
        for (int mm = 0; mm < 4; ++mm) {
            int lrow = qm*64 + ty*4 + mm;
            *(float4*)&tile[lrow*68 + tx*4] = make_float4(
                acc[qm][mm][0], acc[qm][mm][1], acc[qm][mm][2], acc[qm][mm][3]);
        }
#pragma unroll
    for (int it = 0; it < 8; ++it) {
        int idx = it * 256 + tid;
        int d = idx >> 5, l4 = (idx & 31) * 4;
        float4 rv = *(const float4*)(res + ((size_t)b * DD + d) * LL + l0 + l4);
        resb[(l4+0)*72 + d] = f2b(rv.x);
        resb[(l4+1)*72 + d] = f2b(rv.y);
        resb[(l4+2)*72 + d] = f2b(rv.z);
        resb[(l4+3)*72 + d] = f2b(rv.w);
    }
    __syncthreads();
#pragma unroll
    for (int it = 0; it < 4; ++it) {
        int idx = it * 256 + tid;
        int l = idx >> 3, c8 = (idx & 7) * 8;
        unsigned short o[8];
#pragma unroll
        for (int j = 0; j < 8; ++j)
            o[j] = f2b(tile[l*68 + c8 + j] + b2f(resb[l*72 + c8 + j]));
        *(s8v*)&out[((size_t)b * LL + l0 + l) * 64 + c8] = *(s8v*)o;
    }
}

// ---------------------------------------------------------------
// Depthwise causal conv (DC=4) + silu.
// ---------------------------------------------------------------
__global__ __launch_bounds__(256) void k_dwconv(const float* __restrict__ xz,
        const float* __restrict__ w, const float* __restrict__ bias,
        float* __restrict__ xs_act) {
    int idx = blockIdx.x * 256 + threadIdx.x;   // B*L*128
    int d = idx & 127;
    int row = idx >> 7;
    int l = row & (LL - 1);
    float s = bias[d];
    const float* wp = w + d * 4;
#pragma unroll
    for (int j = 0; j < 4; ++j) {
        int li = l - 3 + j;
        if (li >= 0) s += xz[(size_t)(row - 3 + j) * 256 + d] * wp[j];
    }
    float sg = 1.f / (1.f + __expf(-s));
    xs_act[idx] = s * sg;
}

// ---------------------------------------------------------------
// Scan phase 1: thread owns channel d, all 16 states in registers.
// Block = 256 thr = 2 chunks x 128 d. dt_proj fused (1 softplus per t,d).
// dbl tile staged in LDS; xs coalesced from global.
// ---------------------------------------------------------------
__global__ __launch_bounds__(256) void k_scan1(const float* __restrict__ xs,
        const float* __restrict__ dbl, const float* __restrict__ dtw,
        const float* __restrict__ dtbias, const float* __restrict__ A_log,
        float* __restrict__ P, float* __restrict__ Q) {
    __shared__ float sdbl[2][CLEN][64];
    int tid = threadIdx.x;
    int bid = blockIdx.x;
    int b = bid >> 7;
    int cpair = bid & 127;
    int half = tid >> 7;
    int d = tid & 127;
    int c = cpair * 2 + half;
    {
        const float4* src = (const float4*)(dbl +
            ((size_t)b * LL + (size_t)cpair * 2 * CLEN) * 64);
        float4* dst = (float4*)&sdbl[0][0][0];
        dst[tid] = src[tid];
        dst[256 + tid] = src[256 + tid];
    }
    __syncthreads();
    float4 w4 = *(const float4*)(dtw + d * 4);
    float dbias = dtbias[d];
    float Ads[16], h[16], p[16];
#pragma unroll
    for (int s = 0; s < 16; ++s) {
        Ads[s] = -__expf(A_log[d * DSx + s]);
        h[s] = 0.f; p[s] = 1.f;
    }
    size_t rowbase = (size_t)b * LL + (size_t)c * CLEN;
    const float* pxs = xs + rowbase * 128 + d;
    for (int t = 0; t < CLEN; ++t) {
        float4 di = *(const float4*)&sdbl[half][t][0];
        float dtv = di.x*w4.x + di.y*w4.y + di.z*w4.z + di.w*w4.w + dbias;
        dtv = (dtv > 15.f) ? dtv : log1pf(__expf(dtv));
        float xv = pxs[(size_t)t * 128];
        float dx = dtv * xv;
#pragma unroll
        for (int s = 0; s < 16; ++s) {
            float da = __expf(dtv * Ads[s]);
            h[s] = da * h[s] + dx * sdbl[half][t][4 + s];
            p[s] *= da;
        }
    }
    float* Pp = P + (size_t)c * 16384 + (size_t)(b * 128 + d) * 16;
    float* Qp = Q + (size_t)c * 16384 + (size_t)(b * 128 + d) * 16;
#pragma unroll
    for (int s4 = 0; s4 < 4; ++s4) {
        *(float4*)(Pp + s4*4) = make_float4(p[s4*4], p[s4*4+1], p[s4*4+2], p[s4*4+3]);
        *(float4*)(Qp + s4*4) = make_float4(h[s4*4], h[s4*4+1], h[s4*4+2], h[s4*4+3]);
    }
}

// ---------------------------------------------------------------
// Scan phase 2: sequential prefix over chunks + zero BN stats accum.
// ---------------------------------------------------------------
__global__ __launch_bounds__(256) void k_scan2(const float* __restrict__ P,
        const float* __restrict__ Q, float* __restrict__ Hin,
        float* __restrict__ stats) {
    int chain = blockIdx.x * 256 + threadIdx.x;  // 16384
    if (blockIdx.x == 0 && threadIdx.x < 128) stats[threadIdx.x] = 0.f;
    float carry = 0.f;
    for (int c = 0; c < NCH; ++c) {
        Hin[(size_t)c * 16384 + chain] = carry;
        carry = P[(size_t)c * 16384 + chain] * carry + Q[(size_t)c * 16384 + chain];
    }
}

// ---------------------------------------------------------------
// Scan phase 3: thread owns d; no shuffles; emit y (+xs*D, *silu(z)).
// ---------------------------------------------------------------
__global__ __launch_bounds__(256) void k_scan3(const float* __restrict__ xs,
        const float* __restrict__ dbl, const float* __restrict__ dtw,
        const float* __restrict__ dtbias, const float* __restrict__ A_log,
        const float* __restrict__ Hin, const float* __restrict__ xz,
        const float* __restrict__ Dssm, float* __restrict__ ym) {
    __shared__ float sdbl[2][CLEN][64];
    int tid = threadIdx.x;
    int bid = blockIdx.x;
    int b = bid >> 7;
    int cpair = bid & 127;
    int half = tid >> 7;
    int d = tid & 127;
    int c = cpair * 2 + half;
    {
        const float4* src = (const float4*)(dbl +
            ((size_t)b * LL + (size_t)cpair * 2 * CLEN) * 64);
        float4* dst = (float4*)&sdbl[0][0][0];
        dst[tid] = src[tid];
        dst[256 + tid] = src[256 + tid];
    }
    __syncthreads();
    float4 w4 = *(const float4*)(dtw + d * 4);
    float dbias = dtbias[d];
    float Dv = Dssm[d];
    float Ads[16], h[16];
#pragma unroll
    for (int s = 0; s < 16; ++s)
        Ads[s] = -__expf(A_log[d * DSx + s]);
    const float* Hp = Hin + (size_t)c * 16384 + (size_t)(b * 128 + d) * 16;
#pragma unroll
    for (int s4 = 0; s4 < 4; ++s4) {
        float4 hv = *(const float4*)(Hp + s4*4);
        h[s4*4+0] = hv.x; h[s4*4+1] = hv.y; h[s4*4+2] = hv.z; h[s4*4+3] = hv.w;
    }
    size_t rowbase = (size_t)b * LL + (size_t)c * CLEN;
    const float* pxs = xs + rowbase * 128 + d;
    const float* pz  = xz + rowbase * 256 + 128 + d;
    float* pym = ym + rowbase * 128 + d;
    for (int t = 0; t < CLEN; ++t) {
        float4 di = *(const float4*)&sdbl[half][t][0];
        float dtv = di.x*w4.x + di.y*w4.y + di.z*w4.z + di.w*w4.w + dbias;
        dtv = (dtv > 15.f) ? dtv : log1pf(__expf(dtv));
        float xv = pxs[(size_t)t * 128];
        float dx = dtv * xv;
        float y0 = 0.f, y1 = 0.f;
#pragma unroll
        for (int s = 0; s < 8; ++s) {
            float da = __expf(dtv * Ads[s]);
            h[s] = da * h[s] + dx * sdbl[half][t][4 + s];
            y0 += h[s] * sdbl[half][t][20 + s];
        }
#pragma unroll
        for (int s = 8; s < 16; ++s) {
            float da = __expf(dtv * Ads[s]);
            h[s] = da * h[s] + dx * sdbl[half][t][4 + s];
            y1 += h[s] * sdbl[half][t][20 + s];
        }
        float y = y0 + y1 + xv * Dv;
        float zv = pz[(size_t)t * 256];
        y *= zv / (1.f + __expf(-zv));
        pym[(size_t)t * 128] = y;
    }
}

// ---------------------------------------------------------------
// BN partial sums.
// ---------------------------------------------------------------
__global__ __launch_bounds__(256) void k_bnpart(const float* __restrict__ xm,
        float* __restrict__ stats) {
    int c = blockIdx.x >> 3, b = blockIdx.x & 7;
    const float* p = xm + ((size_t)b * DD + c) * LL;
    int tid = threadIdx.x;
    float s = 0.f, ss = 0.f;
#pragma unroll
    for (int it = 0; it < 4; ++it) {
        float4 v = *(const float4*)(p + (size_t)(it * 256 + tid) * 4);
        s  += v.x + v.y + v.z + v.w;
        ss += v.x*v.x + v.y*v.y + v.z*v.z + v.w*v.w;
    }
    for (int o = 32; o > 0; o >>= 1) {
        s  += __shfl_down(s, o);
        ss += __shfl_down(ss, o);
    }
    __shared__ float red[8];
    int wid = tid >> 6;
    if ((tid & 63) == 0) { red[wid] = s; red[4 + wid] = ss; }
    __syncthreads();
    if (tid == 0) {
        atomicAdd(&stats[c], red[0] + red[1] + red[2] + red[3]);
        atomicAdd(&stats[64 + c], red[4] + red[5] + red[6] + red[7]);
    }
}

// ---------------------------------------------------------------
// BN apply + residual + transpose -> bf16 (B,L,64).
// ---------------------------------------------------------------
__global__ __launch_bounds__(256) void k_bnapply_t(const float* __restrict__ xm,
        const float* __restrict__ stats, const float* __restrict__ gamma,
        const float* __restrict__ beta, const float* __restrict__ xin,
        unsigned short* __restrict__ xf) {
    __shared__ float t[64][65];
    int tid = threadIdx.x;
    int b = blockIdx.x >> 6;
    int l0 = (blockIdx.x & 63) * 64;
    const float inv = 1.f / (float)(BB * LL);
#pragma unroll
    for (int it = 0; it < 16; ++it) {
        int idx = it * 256 + tid;
        int c = idx >> 6, l = idx & 63;
        float mean = stats[c] * inv;
        float var  = stats[64 + c] * inv - mean * mean;
        float g = gamma[c] * rsqrtf(var + 1e-5f);
        float sh = beta[c] - mean * g;
        size_t addr = ((size_t)b * DD + c) * LL + l0 + l;
        t[c][l] = xm[addr] * g + sh + xin[addr];
    }
    __syncthreads();
#pragma unroll
    for (int it = 0; it < 2; ++it) {
        int idx = it * 256 + tid;
        int l = idx >> 3, c8 = (idx & 7) * 8;
        unsigned short o[8];
#pragma unroll
        for (int j = 0; j < 8; ++j) o[j] = f2b(t[c8 + j][l]);
        *(s8v*)&xf[((size_t)b * LL + l0 + l) * 64 + c8] = *(s8v*)o;
    }
}

// ---------------------------------------------------------------
// PixelShuffle(r=10) + linear upsample + add, LDS-staged & coalesced.
// Block = (b, c, 256-l tile) -> 2560 contiguous outputs.
// ---------------------------------------------------------------
__global__ __launch_bounds__(256) void k_final(const float* __restrict__ xp,
        const float* __restrict__ x, float* __restrict__ out) {
    __shared__ float xps[10][257];
    __shared__ float xr[258];
    int tid = threadIdx.x;
    int bid = blockIdx.x;
    int lt = bid & 15;
    int c = (bid >> 4) % 12;
    int b = bid / (16 * 12);
    int l0 = lt * 256;
#pragma unroll
    for (int r = 0; r < 10; ++r)
        xps[r][tid] = xp[((size_t)b * 120 + r * 12 + c) * LL + l0 + tid];
    const float* xrow = x + ((size_t)b * 12 + c) * LL;
    for (int i = tid; i < 258; i += 256) {
        int g = l0 - 1 + i;
        g = (g < 0) ? 0 : ((g > LL - 1) ? LL - 1 : g);
        xr[i] = xrow[g];
    }
    __syncthreads();
    size_t obase = ((size_t)b * 12 + c) * OUTL + (size_t)l0 * 10;
#pragma unroll
    for (int u = 0; u < 10; ++u) {
        int j = u * 256 + tid;            // 0..2559
        int jg = l0 * 10 + j;
        int l = j / 10, r = j - l * 10;
        float ps = xps[r][l];
        float src = ((float)jg + 0.5f) * 0.1f - 0.5f;
        src = fmaxf(src, 0.f);
        int i0 = (int)src;
        if (i0 > LL - 1) i0 = LL - 1;
        int i1 = (i0 + 1 < LL) ? i0 + 1 : LL - 1;
        float frac = src - (float)i0;
        float up = xr[i0 - l0 + 1] * (1.f - frac) + xr[i1 - l0 + 1] * frac;
        out[obase + j] = ps + up;
    }
}

// ---------------------------------------------------------------
extern "C" void kernel_launch(void* const* d_in, const int* in_sizes, int n_in,
                              void* d_out, int out_size, void* d_ws, size_t ws_size,
                              hipStream_t stream) {
    const float* x          = (const float*)d_in[0];
    const float* conv_in_w  = (const float*)d_in[1];
    const float* conv_in_b  = (const float*)d_in[2];
    const float* in_proj_w  = (const float*)d_in[3];
    const float* dw_w       = (const float*)d_in[4];
    const float* dw_b       = (const float*)d_in[5];
    const float* x_proj_w   = (const float*)d_in[6];
    const float* dt_w       = (const float*)d_in[7];
    const float* dt_b       = (const float*)d_in[8];
    const float* A_log      = (const float*)d_in[9];
    const float* Dssm       = (const float*)d_in[10];
    const float* out_proj_w = (const float*)d_in[11];
    const float* cm_w       = (const float*)d_in[12];
    const float* cm_b       = (const float*)d_in[13];
    const float* bn_g       = (const float*)d_in[14];
    const float* bn_be      = (const float*)d_in[15];
    const float* ps_w       = (const float*)d_in[16];
    const float* ps_b       = (const float*)d_in[17];

    float* ws = (float*)d_ws;
    float* xin_bdl = ws;                       //  0 .. 2,097,152
    float* xz      = ws + 2097152;             //  .. 10,485,760
    float* xs_act  = ws + 10485760;            //  .. 14,680,064
    float* dbl64   = ws + 14680064;            //  .. 16,777,216
    float* P       = ws + 16777216;            //  .. 20,971,520 (NCH*16384)
    float* Q       = ws + 20971520;            //  .. 25,165,824
    float* Hin     = ws + 25165824;            //  .. 29,360,128
    float* stats   = ws + 29360128;            //  .. 29,360,256
    // aliases (sources dead by the time these are written)
    float* ym      = P;                            // after scan2, P dead
    float* xmerge  = dbl64;                        // after scan3, dbl64 dead
    unsigned short* xmt = (unsigned short*)(ws + 10485760);  // xs_act dead
    unsigned short* xf  = (unsigned short*)(ws + 11534336);
    unsigned short* wp_ps = (unsigned short*)(ws + 6029312); // xz tail, after scan3
    unsigned short* wp_mg = (unsigned short*)(ws + 6090752);
    float* xp      = xz;                           // ps conv out (3.93M floats)

    k_conv<CIN, 64, 2, true><<<1024, 256, 0, stream>>>(x, conv_in_w, conv_in_b, xin_bdl);
    k_gemm_inproj<<<512, 256, 0, stream>>>(xin_bdl, in_proj_w, xz);
    k_dwconv<<<16384, 256, 0, stream>>>(xz, dw_w, dw_b, xs_act);
    k_gemm64<36, true><<<256, 256, 0, stream>>>(xs_act, x_proj_w, dbl64);
    k_scan1<<<1024, 256, 0, stream>>>(xs_act, dbl64, dt_w, dt_b, A_log, P, Q);
    k_scan2<<<64, 256, 0, stream>>>(P, Q, Hin, stats);
    k_scan3<<<1024, 256, 0, stream>>>(xs_act, dbl64, dt_w, dt_b, A_log, Hin, xz, Dssm, ym);
    k_wprep<120, 8><<<480, 256, 0, stream>>>(ps_w, wp_ps);
    k_wprep<64, 4><<<240, 256, 0, stream>>>(cm_w, wp_mg);
    k_gemm64_tr<<<256, 256, 0, stream>>>(ym, out_proj_w, xin_bdl, xmt);
    k_convmfma<64, 4><<<256, 256, 0, stream>>>(xmt, wp_mg, cm_b, xmerge);
    k_bnpart<<<512, 256, 0, stream>>>(xmerge, stats);
    k_bnapply_t<<<512, 256, 0, stream>>>(xmerge, stats, bn_g, bn_be, xin_bdl, xf);
    k_convmfma<120, 8><<<512, 256, 0, stream>>>(xf, wp_ps, ps_b, xp);
    k_final<<<1536, 256, 0, stream>>>(xp, x, (float*)d_out);
}